// Round 4
// baseline (5521.360 us; speedup 1.0000x reference)
//
#include <hip/hip_runtime.h>
#include <hip/hip_bf16.h>
#include <math.h>

#define DIM 384
#define HEADS 12
#define HD 32
#define MLP_H 1536
#define BATCH 8
#define N1 256
#define N2 257
#define SCALE 0.17677669529663687f
#define TIME_SCALE 18.0f

// ------------------------------------------------------------------
// rel bias
// ------------------------------------------------------------------
__global__ __launch_bounds__(256) void rel_kernel(
        const float* __restrict__ x0, const float* __restrict__ w1d,
        const float* __restrict__ b1d, const float* __restrict__ wp,
        const float* __restrict__ bp, float* __restrict__ rel) {
    __shared__ float swp[HD * HD];
    __shared__ float sbp[HD];
    __shared__ float sw1[8];
    __shared__ float sb1;
    __shared__ float sfreq[16];
    int tid = threadIdx.x;
    for (int i = tid; i < HD * HD; i += 256) swp[i] = wp[i];
    if (tid < HD) sbp[tid] = bp[tid];
    if (tid < 8) sw1[tid] = w1d[tid];
    if (tid == 0) sb1 = b1d[0];
    if (tid < 16) sfreq[tid] = expf(-(float)tid * 0.5756462732485114f);
    __syncthreads();

    int gid = blockIdx.x * 256 + tid;
    int j  = gid & (N1 - 1);
    int bi = gid >> 8;
    int i  = bi & (N1 - 1);
    int b  = bi >> 8;

    const float* pi = x0 + (size_t)(b * N1 + i) * 4;
    const float* pj = x0 + (size_t)(b * N1 + j) * 4;
    float dx = pi[0] - pj[0], dy = pi[1] - pj[1], dz = pi[2] - pj[2];
    float dt = pi[3] - pj[3] * TIME_SCALE;
    float dx2 = dx * dx, dy2 = dy * dy, dz2 = dz * dz, dt2 = dt * dt;
    float ds2 = dx2 + dy2 + dz2 - dt2;
    float d = copysignf(sqrtf(fabsf(ds2)), ds2);
    d += dx * sw1[0] + dy * sw1[1] + dz * sw1[2] + dt * sw1[3]
       + dx2 * sw1[4] + dy2 * sw1[5] + dz2 * sw1[6] + dt2 * sw1[7] + sb1;
    d = fminf(fmaxf(d, -4.f), 4.f) * 1024.f;

    float emb[32];
    #pragma unroll
    for (int k = 0; k < 16; k++) {
        float s, c;
        sincosf(d * sfreq[k], &s, &c);
        emb[k] = s; emb[16 + k] = c;
    }
    float* out = rel + (size_t)gid * HD;
    #pragma unroll 4
    for (int c = 0; c < HD; c++) {
        float a = sbp[c];
        #pragma unroll
        for (int k = 0; k < 32; k++) a += emb[k] * swp[c * 32 + k];
        out[c] = a;
    }
}

// ------------------------------------------------------------------
// LayerNorm
// ------------------------------------------------------------------
__global__ __launch_bounds__(128) void ln_kernel(
        const float* __restrict__ x, const float* __restrict__ g,
        const float* __restrict__ b, float* __restrict__ y) {
    int r = blockIdx.x;
    int t = threadIdx.x;
    const float* xr = x + (size_t)r * DIM;
    float v0 = xr[t], v1 = xr[t + 128], v2 = xr[t + 256];
    __shared__ float redm[2], redv[2];
    float s = v0 + v1 + v2;
    for (int o = 32; o; o >>= 1) s += __shfl_down(s, o, 64);
    int lane = t & 63, wid = t >> 6;
    if (!lane) redm[wid] = s;
    __syncthreads();
    float mean = (redm[0] + redm[1]) * (1.f / DIM);
    float d0 = v0 - mean, d1 = v1 - mean, d2 = v2 - mean;
    float s2 = d0 * d0 + d1 * d1 + d2 * d2;
    for (int o = 32; o; o >>= 1) s2 += __shfl_down(s2, o, 64);
    if (!lane) redv[wid] = s2;
    __syncthreads();
    float var = (redv[0] + redv[1]) * (1.f / DIM);
    float rs = rsqrtf(var + 1e-5f);
    float* yr = y + (size_t)r * DIM;
    yr[t]       = d0 * rs * g[t]       + b[t];
    yr[t + 128] = d1 * rs * g[t + 128] + b[t + 128];
    yr[t + 256] = d2 * rs * g[t + 256] + b[t + 256];
}

// ------------------------------------------------------------------
// Generic GEMM (64x64 tile): C = act(A.W^T + bias), opt resid+gate
// ------------------------------------------------------------------
__global__ __launch_bounds__(256) void gemm_kernel(
        const float* __restrict__ A, const float* __restrict__ W,
        const float* __restrict__ bias, const float* __restrict__ resid,
        const float* __restrict__ gvec, float* __restrict__ C,
        int M, int Nn, int K, int do_gelu) {
    __shared__ float As[64][20];
    __shared__ float Ws[64][20];
    int tid = threadIdx.x;
    int n0 = blockIdx.x * 64;
    int m0 = blockIdx.y * 64;
    int tx = tid & 15, ty = tid >> 4;
    int lrow = tid >> 2, lcol = (tid & 3) * 4;

    float acc[4][4];
    #pragma unroll
    for (int a = 0; a < 4; a++)
        #pragma unroll
        for (int bb = 0; bb < 4; bb++) acc[a][bb] = 0.f;

    for (int k0 = 0; k0 < K; k0 += 16) {
        int am = m0 + lrow;
        float4 av = make_float4(0.f, 0.f, 0.f, 0.f);
        if (am < M) av = *(const float4*)(A + (size_t)am * K + k0 + lcol);
        As[lrow][lcol] = av.x; As[lrow][lcol + 1] = av.y;
        As[lrow][lcol + 2] = av.z; As[lrow][lcol + 3] = av.w;
        float4 wv = *(const float4*)(W + (size_t)(n0 + lrow) * K + k0 + lcol);
        Ws[lrow][lcol] = wv.x; Ws[lrow][lcol + 1] = wv.y;
        Ws[lrow][lcol + 2] = wv.z; Ws[lrow][lcol + 3] = wv.w;
        __syncthreads();
        #pragma unroll
        for (int k = 0; k < 16; k += 4) {
            float4 ra[4], rb[4];
            #pragma unroll
            for (int a = 0; a < 4; a++) ra[a] = *(const float4*)&As[ty + 16 * a][k];
            #pragma unroll
            for (int bb = 0; bb < 4; bb++) rb[bb] = *(const float4*)&Ws[tx + 16 * bb][k];
            #pragma unroll
            for (int a = 0; a < 4; a++)
                #pragma unroll
                for (int bb = 0; bb < 4; bb++)
                    acc[a][bb] += ra[a].x * rb[bb].x + ra[a].y * rb[bb].y
                                + ra[a].z * rb[bb].z + ra[a].w * rb[bb].w;
        }
        __syncthreads();
    }
    #pragma unroll
    for (int a = 0; a < 4; a++) {
        int m = m0 + ty + 16 * a;
        if (m >= M) continue;
        #pragma unroll
        for (int bb = 0; bb < 4; bb++) {
            int n = n0 + tx + 16 * bb;
            float v = acc[a][bb];
            if (bias) v += bias[n];
            if (do_gelu) v = 0.5f * v * (1.f + erff(v * 0.70710678118654752f));
            if (resid) {
                float gs = gvec ? gvec[n] : 1.f;
                v = resid[(size_t)m * Nn + n] + gs * v;
            }
            C[(size_t)m * Nn + n] = v;
        }
    }
}

// ------------------------------------------------------------------
// Fused QKV projection
// ------------------------------------------------------------------
__global__ __launch_bounds__(256) void gemm_qkv_kernel(
        const float* __restrict__ A, const float* __restrict__ Wq,
        const float* __restrict__ Wk, const float* __restrict__ Wv,
        float* __restrict__ Oq, float* __restrict__ Ok, float* __restrict__ Ov,
        int M) {
    __shared__ float As[64][20];
    __shared__ float Ws[64][20];
    int tid = threadIdx.x;
    int nb = blockIdx.x;
    int which = nb / 6;
    int n0 = (nb % 6) * 64;
    const float* W = (which == 0) ? Wq : (which == 1) ? Wk : Wv;
    float* C = (which == 0) ? Oq : (which == 1) ? Ok : Ov;
    int m0 = blockIdx.y * 64;
    int tx = tid & 15, ty = tid >> 4;
    int lrow = tid >> 2, lcol = (tid & 3) * 4;

    float acc[4][4];
    #pragma unroll
    for (int a = 0; a < 4; a++)
        #pragma unroll
        for (int bb = 0; bb < 4; bb++) acc[a][bb] = 0.f;

    for (int k0 = 0; k0 < DIM; k0 += 16) {
        int am = m0 + lrow;
        float4 av = make_float4(0.f, 0.f, 0.f, 0.f);
        if (am < M) av = *(const float4*)(A + (size_t)am * DIM + k0 + lcol);
        As[lrow][lcol] = av.x; As[lrow][lcol + 1] = av.y;
        As[lrow][lcol + 2] = av.z; As[lrow][lcol + 3] = av.w;
        float4 wv = *(const float4*)(W + (size_t)(n0 + lrow) * DIM + k0 + lcol);
        Ws[lrow][lcol] = wv.x; Ws[lrow][lcol + 1] = wv.y;
        Ws[lrow][lcol + 2] = wv.z; Ws[lrow][lcol + 3] = wv.w;
        __syncthreads();
        #pragma unroll
        for (int k = 0; k < 16; k += 4) {
            float4 ra[4], rb[4];
            #pragma unroll
            for (int a = 0; a < 4; a++) ra[a] = *(const float4*)&As[ty + 16 * a][k];
            #pragma unroll
            for (int bb = 0; bb < 4; bb++) rb[bb] = *(const float4*)&Ws[tx + 16 * bb][k];
            #pragma unroll
            for (int a = 0; a < 4; a++)
                #pragma unroll
                for (int bb = 0; bb < 4; bb++)
                    acc[a][bb] += ra[a].x * rb[bb].x + ra[a].y * rb[bb].y
                                + ra[a].z * rb[bb].z + ra[a].w * rb[bb].w;
        }
        __syncthreads();
    }
    #pragma unroll
    for (int a = 0; a < 4; a++) {
        int m = m0 + ty + 16 * a;
        if (m >= M) continue;
        #pragma unroll
        for (int bb = 0; bb < 4; bb++) {
            int n = n0 + tx + 16 * bb;
            C[(size_t)m * DIM + n] = acc[a][bb];
        }
    }
}

// ------------------------------------------------------------------
// Attention v4: block = (half, h, b), 512 threads (8 waves).
// K (transposed, pitch 260) and V (row-major, pitch 33) for the whole
// (b,h) staged in LDS ONCE; loop over 32-query chunks with K/V resident.
// HBM traffic is structurally 2x the unique K/V bytes (one per half),
// independent of L2 behavior. LDS ~110 KB -> 1 block/CU.
// ------------------------------------------------------------------
#define KP 260
#define VP 33
__global__ __launch_bounds__(512) void attn_kernel(
        const float* __restrict__ qb, const float* __restrict__ kb,
        const float* __restrict__ vb, const float* __restrict__ relb,
        const float* __restrict__ maskv, float* __restrict__ ob,
        int Nseq, int use_rel) {
    __shared__ float kT[32 * KP];     // 33.3 KB  [c][j]
    __shared__ float vB[260 * VP];    // 34.3 KB  [j][c]
    __shared__ float sc[32][KP];      // 33.3 KB
    __shared__ float qs4[32][32];     // [c][qq]
    __shared__ float qsT[32][32];     // [qq][c]
    __shared__ float ms[288];

    int tid = threadIdx.x;
    int w = tid >> 6, l = tid & 63;
    int half = blockIdx.x, h = blockIdx.y, b = blockIdx.z;
    size_t baseBH = (size_t)(b * Nseq) * DIM + h * HD;

    // ---- stage mask (padded with 0) ----
    for (int j = tid; j < 288; j += 512)
        ms[j] = (j < Nseq) ? maskv[b * Nseq + j] : 0.f;

    // ---- stage K transposed + V row-major (once) ----
    {
        int q4 = tid & 7, r = tid >> 3;
        for (int j = r; j < Nseq; j += 64) {
            float4 kv = *(const float4*)(kb + baseBH + (size_t)j * DIM + q4 * 4);
            kT[(4 * q4 + 0) * KP + j] = kv.x;
            kT[(4 * q4 + 1) * KP + j] = kv.y;
            kT[(4 * q4 + 2) * KP + j] = kv.z;
            kT[(4 * q4 + 3) * KP + j] = kv.w;
            float4 vv = *(const float4*)(vb + baseBH + (size_t)j * DIM + q4 * 4);
            vB[j * VP + 4 * q4 + 0] = vv.x;
            vB[j * VP + 4 * q4 + 1] = vv.y;
            vB[j * VP + 4 * q4 + 2] = vv.z;
            vB[j * VP + 4 * q4 + 3] = vv.w;
        }
        // zero-pad K cols 256..259 and V rows Nseq..259
        if (tid < 128) {
            int cc = tid >> 2, jj = 256 + (tid & 3);
            if (jj >= Nseq) kT[cc * KP + jj] = 0.f;
        }
        for (int t = tid; t < 132; t += 512) {
            int row = 256 + t / VP, cc = t % VP;
            if (row < 260 && row >= Nseq) vB[row * VP + cc] = 0.f;
        }
    }

    int nch = (Nseq + 31) / 32;
    int c0 = (half == 0) ? 0 : (nch + 1) / 2;
    int c1 = (half == 0) ? (nch + 1) / 2 : nch;

    for (int chunk = c0; chunk < c1; chunk++) {
        int i0 = chunk * 32;
        __syncthreads();   // protect qs4/sc from previous chunk readers

        // ---- stage q for this chunk ----
        for (int t = tid; t < 1024; t += 512) {
            int qq = t >> 5, c = t & 31;
            int i = i0 + qq;
            float v = 0.f;
            if (i < Nseq) v = qb[baseBH + (size_t)i * DIM + c] * SCALE;
            qs4[c][qq] = v;
            qsT[qq][c] = v;
        }
        __syncthreads();

        // ---- scores: wave w -> queries 4w..4w+3, lane l -> j=4l..4l+3 ----
        {
            float s[4][4];
            #pragma unroll
            for (int q = 0; q < 4; q++)
                #pragma unroll
                for (int t = 0; t < 4; t++) s[q][t] = 0.f;
            int j0 = 4 * l;
            #pragma unroll 8
            for (int c = 0; c < 32; c++) {
                float4 kq = *(const float4*)&kT[c * KP + j0];
                float4 q4 = *(const float4*)&qs4[c][4 * w];
                s[0][0] += q4.x * kq.x; s[0][1] += q4.x * kq.y; s[0][2] += q4.x * kq.z; s[0][3] += q4.x * kq.w;
                s[1][0] += q4.y * kq.x; s[1][1] += q4.y * kq.y; s[1][2] += q4.y * kq.z; s[1][3] += q4.y * kq.w;
                s[2][0] += q4.z * kq.x; s[2][1] += q4.z * kq.y; s[2][2] += q4.z * kq.z; s[2][3] += q4.z * kq.w;
                s[3][0] += q4.w * kq.x; s[3][1] += q4.w * kq.y; s[3][2] += q4.w * kq.z; s[3][3] += q4.w * kq.w;
            }
            if (use_rel) {                      // Nseq == 256, all i valid
                #pragma unroll
                for (int q = 0; q < 4; q++) {
                    int i = i0 + 4 * w + q;
                    float qr[32];
                    #pragma unroll
                    for (int c4 = 0; c4 < 8; c4++) {
                        float4 t4 = *(const float4*)&qsT[4 * w + q][c4 * 4];
                        qr[4 * c4] = t4.x; qr[4 * c4 + 1] = t4.y;
                        qr[4 * c4 + 2] = t4.z; qr[4 * c4 + 3] = t4.w;
                    }
                    const float* rbase = relb + (((size_t)b * N1 + i) * N1 + j0) * HD;
                    #pragma unroll
                    for (int jj = 0; jj < 4; jj++) {
                        float a = 0.f;
                        #pragma unroll
                        for (int c4 = 0; c4 < 8; c4++) {
                            float4 rv = *(const float4*)(rbase + jj * HD + c4 * 4);
                            a += qr[4 * c4] * rv.x + qr[4 * c4 + 1] * rv.y
                               + qr[4 * c4 + 2] * rv.z + qr[4 * c4 + 3] * rv.w;
                        }
                        s[q][jj] += a;
                    }
                }
            }
            #pragma unroll
            for (int q = 0; q < 4; q++) {
                int i = i0 + 4 * w + q;
                float mi = ms[i];
                float4 o4;
                float mj, mn, mx;
                mj = ms[j0 + 0]; mn = fminf(mi, mj); mx = fmaxf(mi, mj);
                o4.x = s[q][0] + ((mx < 0.f) ? 0.f : mn);
                mj = ms[j0 + 1]; mn = fminf(mi, mj); mx = fmaxf(mi, mj);
                o4.y = s[q][1] + ((mx < 0.f) ? 0.f : mn);
                mj = ms[j0 + 2]; mn = fminf(mi, mj); mx = fmaxf(mi, mj);
                o4.z = s[q][2] + ((mx < 0.f) ? 0.f : mn);
                mj = ms[j0 + 3]; mn = fminf(mi, mj); mx = fmaxf(mi, mj);
                o4.w = s[q][3] + ((mx < 0.f) ? 0.f : mn);
                *(float4*)&sc[4 * w + q][j0] = o4;
            }
            // tail column j = 256 (Nseq == 257)
            if (Nseq > 256) {
                int c = l & 31, h2 = l >> 5;
                float k256 = kT[c * KP + 256];
                float pa = qs4[c][4 * w + 2 * h2]     * k256;
                float pb = qs4[c][4 * w + 2 * h2 + 1] * k256;
                #pragma unroll
                for (int o = 16; o; o >>= 1) {
                    pa += __shfl_xor(pa, o, 32);
                    pb += __shfl_xor(pb, o, 32);
                }
                if ((l & 31) == 0) {
                    int qa = 4 * w + 2 * h2, ia = i0 + qa;
                    float mj = ms[256];
                    float mia = ms[ia], mib = ms[ia + 1];
                    sc[qa][256]     = pa + ((fmaxf(mia, mj) < 0.f) ? 0.f : fminf(mia, mj));
                    sc[qa + 1][256] = pb + ((fmaxf(mib, mj) < 0.f) ? 0.f : fminf(mib, mj));
                }
            }
        }
        __syncthreads();

        // ---- softmax (per wave, per query) ----
        float inv[4];
        #pragma unroll
        for (int q = 0; q < 4; q++) {
            int qq = 4 * w + q;
            float4 sv = *(const float4*)&sc[qq][4 * l];
            float lm = fmaxf(fmaxf(sv.x, sv.y), fmaxf(sv.z, sv.w));
            float s256 = -3.0e38f;
            if (Nseq > 256) s256 = sc[qq][256];
            lm = fmaxf(lm, s256);
            #pragma unroll
            for (int o = 32; o; o >>= 1) lm = fmaxf(lm, __shfl_xor(lm, o, 64));
            float4 ev;
            ev.x = expf(sv.x - lm); ev.y = expf(sv.y - lm);
            ev.z = expf(sv.z - lm); ev.w = expf(sv.w - lm);
            float ls = ev.x + ev.y + ev.z + ev.w;
            #pragma unroll
            for (int o = 32; o; o >>= 1) ls += __shfl_xor(ls, o, 64);
            if (Nseq > 256) {
                float e256 = expf(s256 - lm);
                ls += e256;
                if (l == 0) {
                    float4 t4; t4.x = e256; t4.y = 0.f; t4.z = 0.f; t4.w = 0.f;
                    *(float4*)&sc[qq][256] = t4;
                }
            }
            *(float4*)&sc[qq][4 * l] = ev;
            inv[q] = 1.f / ls;
        }
        __syncthreads();

        // ---- PV: lane = (c, h2); j interleaved quads ----
        {
            int c = l & 31, h2 = l >> 5;
            float acc[4] = {0.f, 0.f, 0.f, 0.f};
            int JMAX = (Nseq > 256) ? 260 : 256;
            for (int j0 = 4 * h2; j0 < JMAX; j0 += 8) {
                float v0 = vB[(j0 + 0) * VP + c];
                float v1 = vB[(j0 + 1) * VP + c];
                float v2 = vB[(j0 + 2) * VP + c];
                float v3 = vB[(j0 + 3) * VP + c];
                #pragma unroll
                for (int q = 0; q < 4; q++) {
                    float4 pv = *(const float4*)&sc[4 * w + q][j0];
                    acc[q] += pv.x * v0 + pv.y * v1 + pv.z * v2 + pv.w * v3;
                    if (use_rel) {
                        int i = i0 + 4 * w + q;
                        const float* rr = relb + (((size_t)b * N1 + i) * N1 + j0) * HD + c;
                        acc[q] += pv.x * rr[0] + pv.y * rr[HD] + pv.z * rr[2 * HD] + pv.w * rr[3 * HD];
                    }
                }
            }
            #pragma unroll
            for (int q = 0; q < 4; q++) {
                float t = __shfl_down(acc[q], 32, 64);
                acc[q] += t;
            }
            if (l < 32) {
                #pragma unroll
                for (int q = 0; q < 4; q++) {
                    int i = i0 + 4 * w + q;
                    if (i < Nseq) ob[baseBH + (size_t)i * DIM + c] = acc[q] * inv[q];
                }
            }
        }
    }
}

// ------------------------------------------------------------------
__global__ __launch_bounds__(256) void concat_kernel(
        const float* __restrict__ xa, const float* __restrict__ clsw,
        const float* __restrict__ mask, float* __restrict__ xb,
        float* __restrict__ m2) {
    int idx = blockIdx.x * 256 + threadIdx.x;
    const int total = BATCH * N2 * DIM;
    if (idx < total) {
        int c = idx % DIM;
        int tokb = idx / DIM;
        int p = tokb % N2, b = tokb / N2;
        xb[idx] = (p == 0) ? clsw[c] : xa[((size_t)(b * N1) + p - 1) * DIM + c];
    }
    if (idx < BATCH * N2) {
        int p = idx % N2, b = idx / N2;
        m2[idx] = (p == 0) ? 0.f : mask[b * N1 + p - 1];
    }
}

__global__ __launch_bounds__(64) void head_kernel(
        const float* __restrict__ xb, const float* __restrict__ ow,
        const float* __restrict__ obv, float* __restrict__ out) {
    int blk = blockIdx.x;
    int b = blk / 3, o = blk % 3;
    int lane = threadIdx.x;
    const float* xr = xb + (size_t)(b * N2) * DIM;
    const float* wr = ow + o * DIM;
    float s = 0.f;
    for (int c = lane; c < DIM; c += 64) s += xr[c] * wr[c];
    for (int off = 32; off; off >>= 1) s += __shfl_down(s, off, 64);
    if (!lane) out[blk] = s + obv[o];
}

// ------------------------------------------------------------------
extern "C" void kernel_launch(void* const* d_in, const int* in_sizes, int n_in,
                              void* d_out, int out_size, void* d_ws, size_t ws_size,
                              hipStream_t stream) {
    (void)in_sizes; (void)n_in; (void)out_size; (void)ws_size;
    const float* X       = (const float*)d_in[0];
    const float* X0      = (const float*)d_in[1];
    const float* MSK     = (const float*)d_in[2];
    const float* RW1     = (const float*)d_in[3];
    const float* RB1     = (const float*)d_in[4];
    const float* RWP     = (const float*)d_in[5];
    const float* RBP     = (const float*)d_in[6];
    const float* SW_LN1G = (const float*)d_in[7];
    const float* SW_LN1B = (const float*)d_in[8];
    const float* SW_LN2G = (const float*)d_in[9];
    const float* SW_LN2B = (const float*)d_in[10];
    const float* SW_WQ   = (const float*)d_in[11];
    const float* SW_WK   = (const float*)d_in[12];
    const float* SW_WV   = (const float*)d_in[13];
    const float* SW_WO   = (const float*)d_in[14];
    const float* SW_BO   = (const float*)d_in[15];
    const float* SW_W1   = (const float*)d_in[16];
    const float* SW_B1   = (const float*)d_in[17];
    const float* SW_W2   = (const float*)d_in[18];
    const float* SW_B2   = (const float*)d_in[19];
    const float* BL_LN1G = (const float*)d_in[20];
    const float* BL_LN1B = (const float*)d_in[21];
    const float* BL_LN2G = (const float*)d_in[22];
    const float* BL_LN2B = (const float*)d_in[23];
    const float* BL_WQ   = (const float*)d_in[24];
    const float* BL_WK   = (const float*)d_in[25];
    const float* BL_WV   = (const float*)d_in[26];
    const float* BL_WO   = (const float*)d_in[27];
    const float* BL_BO   = (const float*)d_in[28];
    const float* BL_W1   = (const float*)d_in[29];
    const float* BL_B1   = (const float*)d_in[30];
    const float* BL_W2   = (const float*)d_in[31];
    const float* BL_B2   = (const float*)d_in[32];
    const float* BL_G1   = (const float*)d_in[33];
    const float* BL_G2   = (const float*)d_in[34];
    const float* CLSW    = (const float*)d_in[35];
    const float* OUTW    = (const float*)d_in[36];
    const float* OUTB    = (const float*)d_in[37];

    const int T1 = BATCH * N1;   // 2048
    const int T2 = BATCH * N2;   // 2056
    const size_t ROWS = (size_t)T2 * DIM;
    const size_t RELSZ = (size_t)BATCH * N1 * N1 * HD;

    float* ws  = (float*)d_ws;
    float* rel = ws;
    float* xa  = rel + RELSZ;
    float* xb  = xa + ROWS;
    float* xn  = xb + ROWS;
    float* qb  = xn + ROWS;
    float* kb  = qb + ROWS;
    float* vb  = kb + ROWS;
    float* ab  = vb + ROWS;
    float* hb  = ab + ROWS;
    float* m2  = hb + (size_t)T2 * MLP_H;

    rel_kernel<<<BATCH * N1 * N1 / 256, 256, 0, stream>>>(X0, RW1, RB1, RWP, RBP, rel);
    hipMemcpyAsync(xa, X, sizeof(float) * T1 * DIM, hipMemcpyDeviceToDevice, stream);

    // ---------------- phase 1: sw layers (N=256) ----------------
    dim3 gP1(DIM / 64, T1 / 64);
    dim3 gQ1(18, T1 / 64);
    dim3 gM1(MLP_H / 64, T1 / 64);
    dim3 gA(2, HEADS, BATCH);                  // 192 blocks, K/V resident
    for (int l = 0; l < 4; l++) {
        const float* wq = SW_WQ + (size_t)l * DIM * DIM;
        const float* wk = SW_WK + (size_t)l * DIM * DIM;
        const float* wv = SW_WV + (size_t)l * DIM * DIM;
        const float* wo = SW_WO + (size_t)l * DIM * DIM;
        const float* bo = SW_BO + (size_t)l * DIM;
        const float* w1 = SW_W1 + (size_t)l * MLP_H * DIM;
        const float* b1 = SW_B1 + (size_t)l * MLP_H;
        const float* w2 = SW_W2 + (size_t)l * DIM * MLP_H;
        const float* b2 = SW_B2 + (size_t)l * DIM;

        ln_kernel<<<T1, 128, 0, stream>>>(xa, SW_LN1G + l * DIM, SW_LN1B + l * DIM, xn);
        gemm_qkv_kernel<<<gQ1, 256, 0, stream>>>(xn, wq, wk, wv, qb, kb, vb, T1);
        attn_kernel<<<gA, 512, 0, stream>>>(qb, kb, vb, rel, MSK, ab, N1, (l == 0) ? 1 : 0);
        gemm_kernel<<<gP1, 256, 0, stream>>>(ab, wo, bo, xa, nullptr, xa, T1, DIM, DIM, 0);
        ln_kernel<<<T1, 128, 0, stream>>>(xa, SW_LN2G + l * DIM, SW_LN2B + l * DIM, xn);
        gemm_kernel<<<gM1, 256, 0, stream>>>(xn, w1, b1, nullptr, nullptr, hb, T1, MLP_H, DIM, 1);
        gemm_kernel<<<gP1, 256, 0, stream>>>(hb, w2, b2, xa, nullptr, xa, T1, DIM, MLP_H, 0);
    }

    // ---------------- concat cls ----------------
    concat_kernel<<<(BATCH * N2 * DIM + 255) / 256, 256, 0, stream>>>(xa, CLSW, MSK, xb, m2);

    // ---------------- phase 2: bl layers (N=257) ----------------
    int MB2 = (T2 + 63) / 64;
    dim3 gP2(DIM / 64, MB2);
    dim3 gQ2(18, MB2);
    dim3 gM2(MLP_H / 64, MB2);
    for (int l = 0; l < 12; l++) {
        const float* wq = BL_WQ + (size_t)l * DIM * DIM;
        const float* wk = BL_WK + (size_t)l * DIM * DIM;
        const float* wv = BL_WV + (size_t)l * DIM * DIM;
        const float* wo = BL_WO + (size_t)l * DIM * DIM;
        const float* bo = BL_BO + (size_t)l * DIM;
        const float* w1 = BL_W1 + (size_t)l * MLP_H * DIM;
        const float* b1 = BL_B1 + (size_t)l * MLP_H;
        const float* w2 = BL_W2 + (size_t)l * DIM * MLP_H;
        const float* b2 = BL_B2 + (size_t)l * DIM;
        const float* g1 = BL_G1 + (size_t)l * DIM;
        const float* g2 = BL_G2 + (size_t)l * DIM;

        ln_kernel<<<T2, 128, 0, stream>>>(xb, BL_LN1G + l * DIM, BL_LN1B + l * DIM, xn);
        gemm_qkv_kernel<<<gQ2, 256, 0, stream>>>(xn, wq, wk, wv, qb, kb, vb, T2);
        attn_kernel<<<gA, 512, 0, stream>>>(qb, kb, vb, nullptr, m2, ab, N2, 0);
        gemm_kernel<<<gP2, 256, 0, stream>>>(ab, wo, bo, xb, g1, xb, T2, DIM, DIM, 0);
        ln_kernel<<<T2, 128, 0, stream>>>(xb, BL_LN2G + l * DIM, BL_LN2B + l * DIM, xn);
        gemm_kernel<<<gM2, 256, 0, stream>>>(xn, w1, b1, nullptr, nullptr, hb, T2, MLP_H, DIM, 1);
        gemm_kernel<<<gP2, 256, 0, stream>>>(hb, w2, b2, xb, g2, xb, T2, DIM, MLP_H, 0);
    }

    // ---------------- head ----------------
    head_kernel<<<BATCH * 3, 64, 0, stream>>>(xb, OUTW, OUTB, (float*)d_out);
}

// Round 5
// 4728.665 us; speedup vs baseline: 1.1676x; 1.1676x over previous
//
#include <hip/hip_runtime.h>
#include <hip/hip_bf16.h>
#include <math.h>

#define DIM 384
#define HEADS 12
#define HD 32
#define MLP_H 1536
#define BATCH 8
#define N1 256
#define N2 257
#define SCALE 0.17677669529663687f
#define TIME_SCALE 18.0f

typedef __attribute__((ext_vector_type(8))) short frag8;
typedef __attribute__((ext_vector_type(4))) float f32x4;

__device__ inline short f2bf(float x) {
    __hip_bfloat16 h = __float2bfloat16(x);
    short s;
    __builtin_memcpy(&s, &h, 2);
    return s;
}

// ------------------------------------------------------------------
// rel bias
// ------------------------------------------------------------------
__global__ __launch_bounds__(256) void rel_kernel(
        const float* __restrict__ x0, const float* __restrict__ w1d,
        const float* __restrict__ b1d, const float* __restrict__ wp,
        const float* __restrict__ bp, float* __restrict__ rel) {
    __shared__ float swp[HD * HD];
    __shared__ float sbp[HD];
    __shared__ float sw1[8];
    __shared__ float sb1;
    __shared__ float sfreq[16];
    int tid = threadIdx.x;
    for (int i = tid; i < HD * HD; i += 256) swp[i] = wp[i];
    if (tid < HD) sbp[tid] = bp[tid];
    if (tid < 8) sw1[tid] = w1d[tid];
    if (tid == 0) sb1 = b1d[0];
    if (tid < 16) sfreq[tid] = expf(-(float)tid * 0.5756462732485114f);
    __syncthreads();

    int gid = blockIdx.x * 256 + tid;
    int j  = gid & (N1 - 1);
    int bi = gid >> 8;
    int i  = bi & (N1 - 1);
    int b  = bi >> 8;

    const float* pi = x0 + (size_t)(b * N1 + i) * 4;
    const float* pj = x0 + (size_t)(b * N1 + j) * 4;
    float dx = pi[0] - pj[0], dy = pi[1] - pj[1], dz = pi[2] - pj[2];
    float dt = pi[3] - pj[3] * TIME_SCALE;
    float dx2 = dx * dx, dy2 = dy * dy, dz2 = dz * dz, dt2 = dt * dt;
    float ds2 = dx2 + dy2 + dz2 - dt2;
    float d = copysignf(sqrtf(fabsf(ds2)), ds2);
    d += dx * sw1[0] + dy * sw1[1] + dz * sw1[2] + dt * sw1[3]
       + dx2 * sw1[4] + dy2 * sw1[5] + dz2 * sw1[6] + dt2 * sw1[7] + sb1;
    d = fminf(fmaxf(d, -4.f), 4.f) * 1024.f;

    float emb[32];
    #pragma unroll
    for (int k = 0; k < 16; k++) {
        float s, c;
        sincosf(d * sfreq[k], &s, &c);
        emb[k] = s; emb[16 + k] = c;
    }
    float* out = rel + (size_t)gid * HD;
    #pragma unroll 4
    for (int c = 0; c < HD; c++) {
        float a = sbp[c];
        #pragma unroll
        for (int k = 0; k < 32; k++) a += emb[k] * swp[c * 32 + k];
        out[c] = a;
    }
}

// ------------------------------------------------------------------
// LayerNorm
// ------------------------------------------------------------------
__global__ __launch_bounds__(128) void ln_kernel(
        const float* __restrict__ x, const float* __restrict__ g,
        const float* __restrict__ b, float* __restrict__ y) {
    int r = blockIdx.x;
    int t = threadIdx.x;
    const float* xr = x + (size_t)r * DIM;
    float v0 = xr[t], v1 = xr[t + 128], v2 = xr[t + 256];
    __shared__ float redm[2], redv[2];
    float s = v0 + v1 + v2;
    for (int o = 32; o; o >>= 1) s += __shfl_down(s, o, 64);
    int lane = t & 63, wid = t >> 6;
    if (!lane) redm[wid] = s;
    __syncthreads();
    float mean = (redm[0] + redm[1]) * (1.f / DIM);
    float d0 = v0 - mean, d1 = v1 - mean, d2 = v2 - mean;
    float s2 = d0 * d0 + d1 * d1 + d2 * d2;
    for (int o = 32; o; o >>= 1) s2 += __shfl_down(s2, o, 64);
    if (!lane) redv[wid] = s2;
    __syncthreads();
    float var = (redv[0] + redv[1]) * (1.f / DIM);
    float rs = rsqrtf(var + 1e-5f);
    float* yr = y + (size_t)r * DIM;
    yr[t]       = d0 * rs * g[t]       + b[t];
    yr[t + 128] = d1 * rs * g[t + 128] + b[t + 128];
    yr[t + 256] = d2 * rs * g[t + 256] + b[t + 256];
}

// ------------------------------------------------------------------
// Generic GEMM (64x64 tile)
// ------------------------------------------------------------------
__global__ __launch_bounds__(256) void gemm_kernel(
        const float* __restrict__ A, const float* __restrict__ W,
        const float* __restrict__ bias, const float* __restrict__ resid,
        const float* __restrict__ gvec, float* __restrict__ C,
        int M, int Nn, int K, int do_gelu) {
    __shared__ float As[64][20];
    __shared__ float Ws[64][20];
    int tid = threadIdx.x;
    int n0 = blockIdx.x * 64;
    int m0 = blockIdx.y * 64;
    int tx = tid & 15, ty = tid >> 4;
    int lrow = tid >> 2, lcol = (tid & 3) * 4;

    float acc[4][4];
    #pragma unroll
    for (int a = 0; a < 4; a++)
        #pragma unroll
        for (int bb = 0; bb < 4; bb++) acc[a][bb] = 0.f;

    for (int k0 = 0; k0 < K; k0 += 16) {
        int am = m0 + lrow;
        float4 av = make_float4(0.f, 0.f, 0.f, 0.f);
        if (am < M) av = *(const float4*)(A + (size_t)am * K + k0 + lcol);
        As[lrow][lcol] = av.x; As[lrow][lcol + 1] = av.y;
        As[lrow][lcol + 2] = av.z; As[lrow][lcol + 3] = av.w;
        float4 wv = *(const float4*)(W + (size_t)(n0 + lrow) * K + k0 + lcol);
        Ws[lrow][lcol] = wv.x; Ws[lrow][lcol + 1] = wv.y;
        Ws[lrow][lcol + 2] = wv.z; Ws[lrow][lcol + 3] = wv.w;
        __syncthreads();
        #pragma unroll
        for (int k = 0; k < 16; k += 4) {
            float4 ra[4], rb[4];
            #pragma unroll
            for (int a = 0; a < 4; a++) ra[a] = *(const float4*)&As[ty + 16 * a][k];
            #pragma unroll
            for (int bb = 0; bb < 4; bb++) rb[bb] = *(const float4*)&Ws[tx + 16 * bb][k];
            #pragma unroll
            for (int a = 0; a < 4; a++)
                #pragma unroll
                for (int bb = 0; bb < 4; bb++)
                    acc[a][bb] += ra[a].x * rb[bb].x + ra[a].y * rb[bb].y
                                + ra[a].z * rb[bb].z + ra[a].w * rb[bb].w;
        }
        __syncthreads();
    }
    #pragma unroll
    for (int a = 0; a < 4; a++) {
        int m = m0 + ty + 16 * a;
        if (m >= M) continue;
        #pragma unroll
        for (int bb = 0; bb < 4; bb++) {
            int n = n0 + tx + 16 * bb;
            float v = acc[a][bb];
            if (bias) v += bias[n];
            if (do_gelu) v = 0.5f * v * (1.f + erff(v * 0.70710678118654752f));
            if (resid) {
                float gs = gvec ? gvec[n] : 1.f;
                v = resid[(size_t)m * Nn + n] + gs * v;
            }
            C[(size_t)m * Nn + n] = v;
        }
    }
}

// ------------------------------------------------------------------
// Fused QKV projection
// ------------------------------------------------------------------
__global__ __launch_bounds__(256) void gemm_qkv_kernel(
        const float* __restrict__ A, const float* __restrict__ Wq,
        const float* __restrict__ Wk, const float* __restrict__ Wv,
        float* __restrict__ Oq, float* __restrict__ Ok, float* __restrict__ Ov,
        int M) {
    __shared__ float As[64][20];
    __shared__ float Ws[64][20];
    int tid = threadIdx.x;
    int nb = blockIdx.x;
    int which = nb / 6;
    int n0 = (nb % 6) * 64;
    const float* W = (which == 0) ? Wq : (which == 1) ? Wk : Wv;
    float* C = (which == 0) ? Oq : (which == 1) ? Ok : Ov;
    int m0 = blockIdx.y * 64;
    int tx = tid & 15, ty = tid >> 4;
    int lrow = tid >> 2, lcol = (tid & 3) * 4;

    float acc[4][4];
    #pragma unroll
    for (int a = 0; a < 4; a++)
        #pragma unroll
        for (int bb = 0; bb < 4; bb++) acc[a][bb] = 0.f;

    for (int k0 = 0; k0 < DIM; k0 += 16) {
        int am = m0 + lrow;
        float4 av = make_float4(0.f, 0.f, 0.f, 0.f);
        if (am < M) av = *(const float4*)(A + (size_t)am * DIM + k0 + lcol);
        As[lrow][lcol] = av.x; As[lrow][lcol + 1] = av.y;
        As[lrow][lcol + 2] = av.z; As[lrow][lcol + 3] = av.w;
        float4 wv = *(const float4*)(W + (size_t)(n0 + lrow) * DIM + k0 + lcol);
        Ws[lrow][lcol] = wv.x; Ws[lrow][lcol + 1] = wv.y;
        Ws[lrow][lcol + 2] = wv.z; Ws[lrow][lcol + 3] = wv.w;
        __syncthreads();
        #pragma unroll
        for (int k = 0; k < 16; k += 4) {
            float4 ra[4], rb[4];
            #pragma unroll
            for (int a = 0; a < 4; a++) ra[a] = *(const float4*)&As[ty + 16 * a][k];
            #pragma unroll
            for (int bb = 0; bb < 4; bb++) rb[bb] = *(const float4*)&Ws[tx + 16 * bb][k];
            #pragma unroll
            for (int a = 0; a < 4; a++)
                #pragma unroll
                for (int bb = 0; bb < 4; bb++)
                    acc[a][bb] += ra[a].x * rb[bb].x + ra[a].y * rb[bb].y
                                + ra[a].z * rb[bb].z + ra[a].w * rb[bb].w;
        }
        __syncthreads();
    }
    #pragma unroll
    for (int a = 0; a < 4; a++) {
        int m = m0 + ty + 16 * a;
        if (m >= M) continue;
        #pragma unroll
        for (int bb = 0; bb < 4; bb++) {
            int n = n0 + tx + 16 * bb;
            C[(size_t)m * DIM + n] = acc[a][bb];
        }
    }
}

// ------------------------------------------------------------------
// MFMA flash attention (no rel). Block = (qgroup of 64, h, b), 256 thr
// (4 waves); wave w owns query rows i0=qg*64+w*16 .. +16.
// K/V staged fragment-major bf16 in LDS (conflict-free ds_read_b128);
// QK^T and PV via mfma_f32_16x16x32_bf16; online softmax per 32-key
// block; P transposed C->A layout through padded per-wave LDS scratch.
// Keys padded to 288 (zeros + -1e9 bias).
// ------------------------------------------------------------------
__global__ __launch_bounds__(256) void attn_mfma_kernel(
        const float* __restrict__ qb, const float* __restrict__ kb,
        const float* __restrict__ vb, const float* __restrict__ maskv,
        float* __restrict__ ob, int Nseq) {
    __shared__ short kf[18][64][8];   // tile t: [quad*16+n][jj] = K[t*16+n][quad*8+jj]
    __shared__ short vf[9][2][64][8]; // [jb][ct][quad*16+n][jj] = V[jb*32+quad*8+jj][ct*16+n]
    __shared__ short pbuf[4][16][40]; // per-wave P scratch, pitch 40 (80B rows)
    __shared__ float ms[304];

    int tid = threadIdx.x;
    int w = tid >> 6, lane = tid & 63;
    int n = lane & 15, quad = lane >> 4;
    int qg = blockIdx.x, h = blockIdx.y, b = blockIdx.z;
    size_t baseBH = (size_t)(b * Nseq) * DIM + h * HD;

    // ---- stage mask ----
    for (int j = tid; j < 304; j += 256)
        ms[j] = (j < Nseq) ? maskv[b * Nseq + j] : 0.f;

    // ---- stage K/V fragment-major (rows >= Nseq zeroed) ----
    {
        int c0 = (tid & 3) * 8;
        for (int j = tid >> 2; j < 288; j += 64) {
            float kv[8], vv[8];
            #pragma unroll
            for (int e = 0; e < 8; e++) { kv[e] = 0.f; vv[e] = 0.f; }
            if (j < Nseq) {
                const float* kr = kb + baseBH + (size_t)j * DIM + c0;
                const float* vr = vb + baseBH + (size_t)j * DIM + c0;
                float4 ka = *(const float4*)kr, kc = *(const float4*)(kr + 4);
                float4 va = *(const float4*)vr, vc = *(const float4*)(vr + 4);
                kv[0] = ka.x; kv[1] = ka.y; kv[2] = ka.z; kv[3] = ka.w;
                kv[4] = kc.x; kv[5] = kc.y; kv[6] = kc.z; kv[7] = kc.w;
                vv[0] = va.x; vv[1] = va.y; vv[2] = va.z; vv[3] = va.w;
                vv[4] = vc.x; vv[5] = vc.y; vv[6] = vc.z; vv[7] = vc.w;
            }
            frag8 kk;
            #pragma unroll
            for (int e = 0; e < 8; e++) kk[e] = f2bf(kv[e]);
            *(frag8*)&kf[j >> 4][(c0 >> 3) * 16 + (j & 15)][0] = kk;
            #pragma unroll
            for (int e = 0; e < 8; e++) {
                int c = c0 + e;
                vf[j >> 5][c >> 4][((j & 31) >> 3) * 16 + (c & 15)][j & 7] = f2bf(vv[e]);
            }
        }
    }

    // ---- load Q A-fragment (regs) ----
    int i0 = qg * 64 + w * 16;
    frag8 qa;
    {
        float qv[8];
        #pragma unroll
        for (int e = 0; e < 8; e++) qv[e] = 0.f;
        int i = i0 + n;
        if (i < Nseq) {
            const float* qr = qb + baseBH + (size_t)i * DIM + quad * 8;
            float4 a = *(const float4*)qr, c = *(const float4*)(qr + 4);
            qv[0] = a.x; qv[1] = a.y; qv[2] = a.z; qv[3] = a.w;
            qv[4] = c.x; qv[5] = c.y; qv[6] = c.z; qv[7] = c.w;
        }
        #pragma unroll
        for (int e = 0; e < 8; e++) qa[e] = f2bf(qv[e] * SCALE);
    }
    __syncthreads();

    float msq[4];
    #pragma unroll
    for (int r = 0; r < 4; r++) msq[r] = ms[i0 + quad * 4 + r];

    float mrow[4], lsum[4];
    #pragma unroll
    for (int r = 0; r < 4; r++) { mrow[r] = -3.0e38f; lsum[r] = 0.f; }
    f32x4 oacc0 = {0.f, 0.f, 0.f, 0.f}, oacc1 = {0.f, 0.f, 0.f, 0.f};

    for (int jb = 0; jb < 9; jb++) {
        frag8 kb0 = *(const frag8*)&kf[2 * jb][lane][0];
        frag8 kb1 = *(const frag8*)&kf[2 * jb + 1][lane][0];
        f32x4 z = {0.f, 0.f, 0.f, 0.f};
        f32x4 s0 = __builtin_amdgcn_mfma_f32_16x16x32_bf16(qa, kb0, z, 0, 0, 0);
        f32x4 s1 = __builtin_amdgcn_mfma_f32_16x16x32_bf16(qa, kb1, z, 0, 0, 0);

        int j0 = jb * 32 + n;
        int j1 = j0 + 16;
        float mj0 = ms[j0], mj1 = ms[j1];
        float pad0 = (j0 < Nseq) ? 0.f : -1e9f;
        float pad1 = (j1 < Nseq) ? 0.f : -1e9f;

        #pragma unroll
        for (int r = 0; r < 4; r++) {
            float mi = msq[r];
            float b0 = ((fmaxf(mi, mj0) < 0.f) ? 0.f : fminf(mi, mj0)) + pad0;
            float b1 = ((fmaxf(mi, mj1) < 0.f) ? 0.f : fminf(mi, mj1)) + pad1;
            float v0 = s0[r] + b0;
            float v1 = s1[r] + b1;
            float rm = fmaxf(v0, v1);
            rm = fmaxf(rm, __shfl_xor(rm, 1));
            rm = fmaxf(rm, __shfl_xor(rm, 2));
            rm = fmaxf(rm, __shfl_xor(rm, 4));
            rm = fmaxf(rm, __shfl_xor(rm, 8));
            float mn = fmaxf(mrow[r], rm);
            float alpha = __expf(mrow[r] - mn);
            mrow[r] = mn;
            float p0 = __expf(v0 - mn);
            float p1 = __expf(v1 - mn);
            float ps = p0 + p1;
            ps += __shfl_xor(ps, 1);
            ps += __shfl_xor(ps, 2);
            ps += __shfl_xor(ps, 4);
            ps += __shfl_xor(ps, 8);
            lsum[r] = lsum[r] * alpha + ps;
            oacc0[r] *= alpha;
            oacc1[r] *= alpha;
            pbuf[w][quad * 4 + r][n]      = f2bf(p0);
            pbuf[w][quad * 4 + r][n + 16] = f2bf(p1);
        }
        __syncthreads();
        frag8 pa = *(const frag8*)&pbuf[w][n][quad * 8];
        frag8 vb0 = *(const frag8*)&vf[jb][0][lane][0];
        frag8 vb1 = *(const frag8*)&vf[jb][1][lane][0];
        oacc0 = __builtin_amdgcn_mfma_f32_16x16x32_bf16(pa, vb0, oacc0, 0, 0, 0);
        oacc1 = __builtin_amdgcn_mfma_f32_16x16x32_bf16(pa, vb1, oacc1, 0, 0, 0);
        __syncthreads();
    }

    // ---- store ----
    #pragma unroll
    for (int r = 0; r < 4; r++) {
        int i = i0 + quad * 4 + r;
        if (i < Nseq) {
            float invl = 1.f / lsum[r];
            ob[baseBH + (size_t)i * DIM + n]      = oacc0[r] * invl;
            ob[baseBH + (size_t)i * DIM + 16 + n] = oacc1[r] * invl;
        }
    }
}

// ------------------------------------------------------------------
// fp32 attention with rel bias (layer 0 only) — verified R4 kernel
// ------------------------------------------------------------------
#define KP 260
#define VP 33
__global__ __launch_bounds__(512) void attn_kernel(
        const float* __restrict__ qb, const float* __restrict__ kb,
        const float* __restrict__ vb, const float* __restrict__ relb,
        const float* __restrict__ maskv, float* __restrict__ ob,
        int Nseq, int use_rel) {
    __shared__ float kT[32 * KP];
    __shared__ float vB[260 * VP];
    __shared__ float sc[32][KP];
    __shared__ float qs4[32][32];
    __shared__ float qsT[32][32];
    __shared__ float ms[288];

    int tid = threadIdx.x;
    int w = tid >> 6, l = tid & 63;
    int half = blockIdx.x, h = blockIdx.y, b = blockIdx.z;
    size_t baseBH = (size_t)(b * Nseq) * DIM + h * HD;

    for (int j = tid; j < 288; j += 512)
        ms[j] = (j < Nseq) ? maskv[b * Nseq + j] : 0.f;

    {
        int q4 = tid & 7, r = tid >> 3;
        for (int j = r; j < Nseq; j += 64) {
            float4 kv = *(const float4*)(kb + baseBH + (size_t)j * DIM + q4 * 4);
            kT[(4 * q4 + 0) * KP + j] = kv.x;
            kT[(4 * q4 + 1) * KP + j] = kv.y;
            kT[(4 * q4 + 2) * KP + j] = kv.z;
            kT[(4 * q4 + 3) * KP + j] = kv.w;
            float4 vv = *(const float4*)(vb + baseBH + (size_t)j * DIM + q4 * 4);
            vB[j * VP + 4 * q4 + 0] = vv.x;
            vB[j * VP + 4 * q4 + 1] = vv.y;
            vB[j * VP + 4 * q4 + 2] = vv.z;
            vB[j * VP + 4 * q4 + 3] = vv.w;
        }
        if (tid < 128) {
            int cc = tid >> 2, jj = 256 + (tid & 3);
            if (jj >= Nseq) kT[cc * KP + jj] = 0.f;
        }
        for (int t = tid; t < 132; t += 512) {
            int row = 256 + t / VP, cc = t % VP;
            if (row < 260 && row >= Nseq) vB[row * VP + cc] = 0.f;
        }
    }

    int nch = (Nseq + 31) / 32;
    int c0 = (half == 0) ? 0 : (nch + 1) / 2;
    int c1 = (half == 0) ? (nch + 1) / 2 : nch;

    for (int chunk = c0; chunk < c1; chunk++) {
        int i0 = chunk * 32;
        __syncthreads();

        for (int t = tid; t < 1024; t += 512) {
            int qq = t >> 5, c = t & 31;
            int i = i0 + qq;
            float v = 0.f;
            if (i < Nseq) v = qb[baseBH + (size_t)i * DIM + c] * SCALE;
            qs4[c][qq] = v;
            qsT[qq][c] = v;
        }
        __syncthreads();

        {
            float s[4][4];
            #pragma unroll
            for (int q = 0; q < 4; q++)
                #pragma unroll
                for (int t = 0; t < 4; t++) s[q][t] = 0.f;
            int j0 = 4 * l;
            #pragma unroll 8
            for (int c = 0; c < 32; c++) {
                float4 kq = *(const float4*)&kT[c * KP + j0];
                float4 q4 = *(const float4*)&qs4[c][4 * w];
                s[0][0] += q4.x * kq.x; s[0][1] += q4.x * kq.y; s[0][2] += q4.x * kq.z; s[0][3] += q4.x * kq.w;
                s[1][0] += q4.y * kq.x; s[1][1] += q4.y * kq.y; s[1][2] += q4.y * kq.z; s[1][3] += q4.y * kq.w;
                s[2][0] += q4.z * kq.x; s[2][1] += q4.z * kq.y; s[2][2] += q4.z * kq.z; s[2][3] += q4.z * kq.w;
                s[3][0] += q4.w * kq.x; s[3][1] += q4.w * kq.y; s[3][2] += q4.w * kq.z; s[3][3] += q4.w * kq.w;
            }
            if (use_rel) {
                #pragma unroll
                for (int q = 0; q < 4; q++) {
                    int i = i0 + 4 * w + q;
                    float qr[32];
                    #pragma unroll
                    for (int c4 = 0; c4 < 8; c4++) {
                        float4 t4 = *(const float4*)&qsT[4 * w + q][c4 * 4];
                        qr[4 * c4] = t4.x; qr[4 * c4 + 1] = t4.y;
                        qr[4 * c4 + 2] = t4.z; qr[4 * c4 + 3] = t4.w;
                    }
                    const float* rbase = relb + (((size_t)b * N1 + i) * N1 + j0) * HD;
                    #pragma unroll
                    for (int jj = 0; jj < 4; jj++) {
                        float a = 0.f;
                        #pragma unroll
                        for (int c4 = 0; c4 < 8; c4++) {
                            float4 rv = *(const float4*)(rbase + jj * HD + c4 * 4);
                            a += qr[4 * c4] * rv.x + qr[4 * c4 + 1] * rv.y
                               + qr[4 * c4 + 2] * rv.z + qr[4 * c4 + 3] * rv.w;
                        }
                        s[q][jj] += a;
                    }
                }
            }
            #pragma unroll
            for (int q = 0; q < 4; q++) {
                int i = i0 + 4 * w + q;
                float mi = ms[i];
                float4 o4;
                float mj, mn, mx;
                mj = ms[j0 + 0]; mn = fminf(mi, mj); mx = fmaxf(mi, mj);
                o4.x = s[q][0] + ((mx < 0.f) ? 0.f : mn);
                mj = ms[j0 + 1]; mn = fminf(mi, mj); mx = fmaxf(mi, mj);
                o4.y = s[q][1] + ((mx < 0.f) ? 0.f : mn);
                mj = ms[j0 + 2]; mn = fminf(mi, mj); mx = fmaxf(mi, mj);
                o4.z = s[q][2] + ((mx < 0.f) ? 0.f : mn);
                mj = ms[j0 + 3]; mn = fminf(mi, mj); mx = fmaxf(mi, mj);
                o4.w = s[q][3] + ((mx < 0.f) ? 0.f : mn);
                *(float4*)&sc[4 * w + q][j0] = o4;
            }
            if (Nseq > 256) {
                int c = l & 31, h2 = l >> 5;
                float k256 = kT[c * KP + 256];
                float pa = qs4[c][4 * w + 2 * h2]     * k256;
                float pb = qs4[c][4 * w + 2 * h2 + 1] * k256;
                #pragma unroll
                for (int o = 16; o; o >>= 1) {
                    pa += __shfl_xor(pa, o, 32);
                    pb += __shfl_xor(pb, o, 32);
                }
                if ((l & 31) == 0) {
                    int qa = 4 * w + 2 * h2, ia = i0 + qa;
                    float mj = ms[256];
                    float mia = ms[ia], mib = ms[ia + 1];
                    sc[qa][256]     = pa + ((fmaxf(mia, mj) < 0.f) ? 0.f : fminf(mia, mj));
                    sc[qa + 1][256] = pb + ((fmaxf(mib, mj) < 0.f) ? 0.f : fminf(mib, mj));
                }
            }
        }
        __syncthreads();

        float inv[4];
        #pragma unroll
        for (int q = 0; q < 4; q++) {
            int qq = 4 * w + q;
            float4 sv = *(const float4*)&sc[qq][4 * l];
            float lm = fmaxf(fmaxf(sv.x, sv.y), fmaxf(sv.z, sv.w));
            float s256 = -3.0e38f;
            if (Nseq > 256) s256 = sc[qq][256];
            lm = fmaxf(lm, s256);
            #pragma unroll
            for (int o = 32; o; o >>= 1) lm = fmaxf(lm, __shfl_xor(lm, o, 64));
            float4 ev;
            ev.x = expf(sv.x - lm); ev.y = expf(sv.y - lm);
            ev.z = expf(sv.z - lm); ev.w = expf(sv.w - lm);
            float ls = ev.x + ev.y + ev.z + ev.w;
            #pragma unroll
            for (int o = 32; o; o >>= 1) ls += __shfl_xor(ls, o, 64);
            if (Nseq > 256) {
                float e256 = expf(s256 - lm);
                ls += e256;
                if (l == 0) {
                    float4 t4; t4.x = e256; t4.y = 0.f; t4.z = 0.f; t4.w = 0.f;
                    *(float4*)&sc[qq][256] = t4;
                }
            }
            *(float4*)&sc[qq][4 * l] = ev;
            inv[q] = 1.f / ls;
        }
        __syncthreads();

        {
            int c = l & 31, h2 = l >> 5;
            float acc[4] = {0.f, 0.f, 0.f, 0.f};
            int JMAX = (Nseq > 256) ? 260 : 256;
            for (int j0 = 4 * h2; j0 < JMAX; j0 += 8) {
                float v0 = vB[(j0 + 0) * VP + c];
                float v1 = vB[(j0 + 1) * VP + c];
                float v2 = vB[(j0 + 2) * VP + c];
                float v3 = vB[(j0 + 3) * VP + c];
                #pragma unroll
                for (int q = 0; q < 4; q++) {
                    float4 pv = *(const float4*)&sc[4 * w + q][j0];
                    acc[q] += pv.x * v0 + pv.y * v1 + pv.z * v2 + pv.w * v3;
                    if (use_rel) {
                        int i = i0 + 4 * w + q;
                        const float* rr = relb + (((size_t)b * N1 + i) * N1 + j0) * HD + c;
                        acc[q] += pv.x * rr[0] + pv.y * rr[HD] + pv.z * rr[2 * HD] + pv.w * rr[3 * HD];
                    }
                }
            }
            #pragma unroll
            for (int q = 0; q < 4; q++) {
                float t = __shfl_down(acc[q], 32, 64);
                acc[q] += t;
            }
            if (l < 32) {
                #pragma unroll
                for (int q = 0; q < 4; q++) {
                    int i = i0 + 4 * w + q;
                    if (i < Nseq) ob[baseBH + (size_t)i * DIM + c] = acc[q] * inv[q];
                }
            }
        }
    }
}

// ------------------------------------------------------------------
__global__ __launch_bounds__(256) void concat_kernel(
        const float* __restrict__ xa, const float* __restrict__ clsw,
        const float* __restrict__ mask, float* __restrict__ xb,
        float* __restrict__ m2) {
    int idx = blockIdx.x * 256 + threadIdx.x;
    const int total = BATCH * N2 * DIM;
    if (idx < total) {
        int c = idx % DIM;
        int tokb = idx / DIM;
        int p = tokb % N2, b = tokb / N2;
        xb[idx] = (p == 0) ? clsw[c] : xa[((size_t)(b * N1) + p - 1) * DIM + c];
    }
    if (idx < BATCH * N2) {
        int p = idx % N2, b = idx / N2;
        m2[idx] = (p == 0) ? 0.f : mask[b * N1 + p - 1];
    }
}

__global__ __launch_bounds__(64) void head_kernel(
        const float* __restrict__ xb, const float* __restrict__ ow,
        const float* __restrict__ obv, float* __restrict__ out) {
    int blk = blockIdx.x;
    int b = blk / 3, o = blk % 3;
    int lane = threadIdx.x;
    const float* xr = xb + (size_t)(b * N2) * DIM;
    const float* wr = ow + o * DIM;
    float s = 0.f;
    for (int c = lane; c < DIM; c += 64) s += xr[c] * wr[c];
    for (int off = 32; off; off >>= 1) s += __shfl_down(s, off, 64);
    if (!lane) out[blk] = s + obv[o];
}

// ------------------------------------------------------------------
extern "C" void kernel_launch(void* const* d_in, const int* in_sizes, int n_in,
                              void* d_out, int out_size, void* d_ws, size_t ws_size,
                              hipStream_t stream) {
    (void)in_sizes; (void)n_in; (void)out_size; (void)ws_size;
    const float* X       = (const float*)d_in[0];
    const float* X0      = (const float*)d_in[1];
    const float* MSK     = (const float*)d_in[2];
    const float* RW1     = (const float*)d_in[3];
    const float* RB1     = (const float*)d_in[4];
    const float* RWP     = (const float*)d_in[5];
    const float* RBP     = (const float*)d_in[6];
    const float* SW_LN1G = (const float*)d_in[7];
    const float* SW_LN1B = (const float*)d_in[8];
    const float* SW_LN2G = (const float*)d_in[9];
    const float* SW_LN2B = (const float*)d_in[10];
    const float* SW_WQ   = (const float*)d_in[11];
    const float* SW_WK   = (const float*)d_in[12];
    const float* SW_WV   = (const float*)d_in[13];
    const float* SW_WO   = (const float*)d_in[14];
    const float* SW_BO   = (const float*)d_in[15];
    const float* SW_W1   = (const float*)d_in[16];
    const float* SW_B1   = (const float*)d_in[17];
    const float* SW_W2   = (const float*)d_in[18];
    const float* SW_B2   = (const float*)d_in[19];
    const float* BL_LN1G = (const float*)d_in[20];
    const float* BL_LN1B = (const float*)d_in[21];
    const float* BL_LN2G = (const float*)d_in[22];
    const float* BL_LN2B = (const float*)d_in[23];
    const float* BL_WQ   = (const float*)d_in[24];
    const float* BL_WK   = (const float*)d_in[25];
    const float* BL_WV   = (const float*)d_in[26];
    const float* BL_WO   = (const float*)d_in[27];
    const float* BL_BO   = (const float*)d_in[28];
    const float* BL_W1   = (const float*)d_in[29];
    const float* BL_B1   = (const float*)d_in[30];
    const float* BL_W2   = (const float*)d_in[31];
    const float* BL_B2   = (const float*)d_in[32];
    const float* BL_G1   = (const float*)d_in[33];
    const float* BL_G2   = (const float*)d_in[34];
    const float* CLSW    = (const float*)d_in[35];
    const float* OUTW    = (const float*)d_in[36];
    const float* OUTB    = (const float*)d_in[37];

    const int T1 = BATCH * N1;   // 2048
    const int T2 = BATCH * N2;   // 2056
    const size_t ROWS = (size_t)T2 * DIM;
    const size_t RELSZ = (size_t)BATCH * N1 * N1 * HD;

    float* ws  = (float*)d_ws;
    float* rel = ws;
    float* xa  = rel + RELSZ;
    float* xb  = xa + ROWS;
    float* xn  = xb + ROWS;
    float* qb  = xn + ROWS;
    float* kb  = qb + ROWS;
    float* vb  = kb + ROWS;
    float* ab  = vb + ROWS;
    float* hb  = ab + ROWS;
    float* m2  = hb + (size_t)T2 * MLP_H;

    rel_kernel<<<BATCH * N1 * N1 / 256, 256, 0, stream>>>(X0, RW1, RB1, RWP, RBP, rel);
    hipMemcpyAsync(xa, X, sizeof(float) * T1 * DIM, hipMemcpyDeviceToDevice, stream);

    // ---------------- phase 1: sw layers (N=256) ----------------
    dim3 gP1(DIM / 64, T1 / 64);
    dim3 gQ1(18, T1 / 64);
    dim3 gM1(MLP_H / 64, T1 / 64);
    dim3 gRel(2, HEADS, BATCH);
    dim3 gF1(4, HEADS, BATCH);                  // 64-query groups
    for (int l = 0; l < 4; l++) {
        const float* wq = SW_WQ + (size_t)l * DIM * DIM;
        const float* wk = SW_WK + (size_t)l * DIM * DIM;
        const float* wv = SW_WV + (size_t)l * DIM * DIM;
        const float* wo = SW_WO + (size_t)l * DIM * DIM;
        const float* bo = SW_BO + (size_t)l * DIM;
        const float* w1 = SW_W1 + (size_t)l * MLP_H * DIM;
        const float* b1 = SW_B1 + (size_t)l * MLP_H;
        const float* w2 = SW_W2 + (size_t)l * DIM * MLP_H;
        const float* b2 = SW_B2 + (size_t)l * DIM;

        ln_kernel<<<T1, 128, 0, stream>>>(xa, SW_LN1G + l * DIM, SW_LN1B + l * DIM, xn);
        gemm_qkv_kernel<<<gQ1, 256, 0, stream>>>(xn, wq, wk, wv, qb, kb, vb, T1);
        if (l == 0)
            attn_kernel<<<gRel, 512, 0, stream>>>(qb, kb, vb, rel, MSK, ab, N1, 1);
        else
            attn_mfma_kernel<<<gF1, 256, 0, stream>>>(qb, kb, vb, MSK, ab, N1);
        gemm_kernel<<<gP1, 256, 0, stream>>>(ab, wo, bo, xa, nullptr, xa, T1, DIM, DIM, 0);
        ln_kernel<<<T1, 128, 0, stream>>>(xa, SW_LN2G + l * DIM, SW_LN2B + l * DIM, xn);
        gemm_kernel<<<gM1, 256, 0, stream>>>(xn, w1, b1, nullptr, nullptr, hb, T1, MLP_H, DIM, 1);
        gemm_kernel<<<gP1, 256, 0, stream>>>(hb, w2, b2, xa, nullptr, xa, T1, DIM, MLP_H, 0);
    }

    // ---------------- concat cls ----------------
    concat_kernel<<<(BATCH * N2 * DIM + 255) / 256, 256, 0, stream>>>(xa, CLSW, MSK, xb, m2);

    // ---------------- phase 2: bl layers (N=257) ----------------
    int MB2 = (T2 + 63) / 64;
    dim3 gP2(DIM / 64, MB2);
    dim3 gQ2(18, MB2);
    dim3 gM2(MLP_H / 64, MB2);
    dim3 gF2(5, HEADS, BATCH);                  // ceil(257/64) = 5
    for (int l = 0; l < 12; l++) {
        const float* wq = BL_WQ + (size_t)l * DIM * DIM;
        const float* wk = BL_WK + (size_t)l * DIM * DIM;
        const float* wv = BL_WV + (size_t)l * DIM * DIM;
        const float* wo = BL_WO + (size_t)l * DIM * DIM;
        const float* bo = BL_BO + (size_t)l * DIM;
        const float* w1 = BL_W1 + (size_t)l * MLP_H * DIM;
        const float* b1 = BL_B1 + (size_t)l * MLP_H;
        const float* w2 = BL_W2 + (size_t)l * DIM * MLP_H;
        const float* b2 = BL_B2 + (size_t)l * DIM;
        const float* g1 = BL_G1 + (size_t)l * DIM;
        const float* g2 = BL_G2 + (size_t)l * DIM;

        ln_kernel<<<T2, 128, 0, stream>>>(xb, BL_LN1G + l * DIM, BL_LN1B + l * DIM, xn);
        gemm_qkv_kernel<<<gQ2, 256, 0, stream>>>(xn, wq, wk, wv, qb, kb, vb, T2);
        attn_mfma_kernel<<<gF2, 256, 0, stream>>>(qb, kb, vb, m2, ab, N2);
        gemm_kernel<<<gP2, 256, 0, stream>>>(ab, wo, bo, xb, g1, xb, T2, DIM, DIM, 0);
        ln_kernel<<<T2, 128, 0, stream>>>(xb, BL_LN2G + l * DIM, BL_LN2B + l * DIM, xn);
        gemm_kernel<<<gM2, 256, 0, stream>>>(xn, w1, b1, nullptr, nullptr, hb, T2, MLP_H, DIM, 1);
        gemm_kernel<<<gP2, 256, 0, stream>>>(hb, w2, b2, xb, g2, xb, T2, DIM, MLP_H, 0);
    }

    // ---------------- head ----------------
    head_kernel<<<BATCH * 3, 64, 0, stream>>>(xb, OUTW, OUTB, (float*)d_out);
}

// Round 6
// 2118.812 us; speedup vs baseline: 2.6059x; 2.2318x over previous
//
#include <hip/hip_runtime.h>
#include <hip/hip_bf16.h>
#include <math.h>

#define DIM 384
#define HEADS 12
#define HD 32
#define MLP_H 1536
#define BATCH 8
#define N1 256
#define N2 257
#define QP 1152          // fused qkv row pitch (shorts)
#define SCALE 0.17677669529663687f
#define TIME_SCALE 18.0f

typedef __attribute__((ext_vector_type(8))) short frag8;
typedef __attribute__((ext_vector_type(4))) float f32x4;

__device__ inline short f2bf(float x) {
    __hip_bfloat16 h = __float2bfloat16(x);
    short s;
    __builtin_memcpy(&s, &h, 2);
    return s;
}
__device__ inline float bf2f(short s) {
    unsigned u = ((unsigned)(unsigned short)s) << 16;
    float f;
    __builtin_memcpy(&f, &u, 4);
    return f;
}

// ------------------------------------------------------------------
// weight conversion: fp32 -> bf16 (plain)
// ------------------------------------------------------------------
__global__ __launch_bounds__(256) void conv_kernel(
        const float* __restrict__ in, short* __restrict__ out, int n) {
    int i = (blockIdx.x * 256 + threadIdx.x) * 4;
    if (i >= n) return;
    float4 v = *(const float4*)(in + i);
    out[i]     = f2bf(v.x);
    out[i + 1] = f2bf(v.y);
    out[i + 2] = f2bf(v.z);
    out[i + 3] = f2bf(v.w);
}

// gather-convert: per layer pack [wq;wk;wv] -> (L,1152,384) bf16
__global__ __launch_bounds__(256) void conv_qkv_kernel(
        const float* __restrict__ wq, const float* __restrict__ wk,
        const float* __restrict__ wv, short* __restrict__ out, int L) {
    size_t idx = ((size_t)blockIdx.x * 256 + threadIdx.x) * 4;
    size_t total = (size_t)L * QP * DIM;
    if (idx >= total) return;
    size_t k = idx % DIM;
    size_t row = idx / DIM;
    size_t r = row % QP;
    size_t l = row / QP;
    int which = (int)(r / DIM);
    int rr = (int)(r % DIM);
    const float* src = ((which == 0) ? wq : (which == 1) ? wk : wv)
                     + (l * DIM + rr) * DIM + k;
    float4 v = *(const float4*)src;
    out[idx]     = f2bf(v.x);
    out[idx + 1] = f2bf(v.y);
    out[idx + 2] = f2bf(v.z);
    out[idx + 3] = f2bf(v.w);
}

// ------------------------------------------------------------------
// rel bias (fp32, unchanged)
// ------------------------------------------------------------------
__global__ __launch_bounds__(256) void rel_kernel(
        const float* __restrict__ x0, const float* __restrict__ w1d,
        const float* __restrict__ b1d, const float* __restrict__ wp,
        const float* __restrict__ bp, float* __restrict__ rel) {
    __shared__ float swp[HD * HD];
    __shared__ float sbp[HD];
    __shared__ float sw1[8];
    __shared__ float sb1;
    __shared__ float sfreq[16];
    int tid = threadIdx.x;
    for (int i = tid; i < HD * HD; i += 256) swp[i] = wp[i];
    if (tid < HD) sbp[tid] = bp[tid];
    if (tid < 8) sw1[tid] = w1d[tid];
    if (tid == 0) sb1 = b1d[0];
    if (tid < 16) sfreq[tid] = expf(-(float)tid * 0.5756462732485114f);
    __syncthreads();

    int gid = blockIdx.x * 256 + tid;
    int j  = gid & (N1 - 1);
    int bi = gid >> 8;
    int i  = bi & (N1 - 1);
    int b  = bi >> 8;

    const float* pi = x0 + (size_t)(b * N1 + i) * 4;
    const float* pj = x0 + (size_t)(b * N1 + j) * 4;
    float dx = pi[0] - pj[0], dy = pi[1] - pj[1], dz = pi[2] - pj[2];
    float dt = pi[3] - pj[3] * TIME_SCALE;
    float dx2 = dx * dx, dy2 = dy * dy, dz2 = dz * dz, dt2 = dt * dt;
    float ds2 = dx2 + dy2 + dz2 - dt2;
    float d = copysignf(sqrtf(fabsf(ds2)), ds2);
    d += dx * sw1[0] + dy * sw1[1] + dz * sw1[2] + dt * sw1[3]
       + dx2 * sw1[4] + dy2 * sw1[5] + dz2 * sw1[6] + dt2 * sw1[7] + sb1;
    d = fminf(fmaxf(d, -4.f), 4.f) * 1024.f;

    float emb[32];
    #pragma unroll
    for (int k = 0; k < 16; k++) {
        float s, c;
        sincosf(d * sfreq[k], &s, &c);
        emb[k] = s; emb[16 + k] = c;
    }
    float* out = rel + (size_t)gid * HD;
    #pragma unroll 4
    for (int c = 0; c < HD; c++) {
        float a = sbp[c];
        #pragma unroll
        for (int k = 0; k < 32; k++) a += emb[k] * swp[c * 32 + k];
        out[c] = a;
    }
}

// ------------------------------------------------------------------
// LayerNorm: fp32 in -> bf16 out
// ------------------------------------------------------------------
__global__ __launch_bounds__(128) void ln_kernel(
        const float* __restrict__ x, const float* __restrict__ g,
        const float* __restrict__ b, short* __restrict__ y) {
    int r = blockIdx.x;
    int t = threadIdx.x;
    const float* xr = x + (size_t)r * DIM;
    float v0 = xr[t], v1 = xr[t + 128], v2 = xr[t + 256];
    __shared__ float redm[2], redv[2];
    float s = v0 + v1 + v2;
    for (int o = 32; o; o >>= 1) s += __shfl_down(s, o, 64);
    int lane = t & 63, wid = t >> 6;
    if (!lane) redm[wid] = s;
    __syncthreads();
    float mean = (redm[0] + redm[1]) * (1.f / DIM);
    float d0 = v0 - mean, d1 = v1 - mean, d2 = v2 - mean;
    float s2 = d0 * d0 + d1 * d1 + d2 * d2;
    for (int o = 32; o; o >>= 1) s2 += __shfl_down(s2, o, 64);
    if (!lane) redv[wid] = s2;
    __syncthreads();
    float var = (redv[0] + redv[1]) * (1.f / DIM);
    float rs = rsqrtf(var + 1e-5f);
    short* yr = y + (size_t)r * DIM;
    yr[t]       = f2bf(d0 * rs * g[t]       + b[t]);
    yr[t + 128] = f2bf(d1 * rs * g[t + 128] + b[t + 128]);
    yr[t + 256] = f2bf(d2 * rs * g[t + 256] + b[t + 256]);
}

// ------------------------------------------------------------------
// bf16 MFMA GEMM: C = act(A.W^T [+bias]) [+resid(+gate)]
// A (M,K) bf16 row-major, W (N,K) bf16 row-major.
// 64x64 tile, BK=64, 4 waves x (32x32). Fragment-major LDS.
// mode 0: ->bf16 Cb (no bias). mode 1: bias+GELU ->bf16 Cb.
// mode 2: bias + resid (+gate) ->fp32 Cf.
// ------------------------------------------------------------------
__global__ __launch_bounds__(256) void gemm_bf16_kernel(
        const short* __restrict__ A, const short* __restrict__ W,
        const float* __restrict__ bias, const float* __restrict__ resid,
        const float* __restrict__ gvec, float* __restrict__ Cf,
        short* __restrict__ Cb, int M, int Np, int K, int mode) {
    __shared__ short As[2][4][64][8];   // [ks][q][row][j]
    __shared__ short Bs[2][4][64][8];
    int tid = threadIdx.x;
    int w = tid >> 6, lane = tid & 63;
    int nlo = lane & 15, quad = lane >> 4;
    int wm = w >> 1, wn = w & 1;
    int n0 = blockIdx.x * 64, m0 = blockIdx.y * 64;

    f32x4 acc[2][2];
    #pragma unroll
    for (int a = 0; a < 2; a++)
        #pragma unroll
        for (int c = 0; c < 2; c++) acc[a][c] = (f32x4){0.f, 0.f, 0.f, 0.f};

    int chunk = tid & 7, ks_s = chunk >> 2, q_s = chunk & 3;
    int rbase = tid >> 3;                // 0..31

    for (int k0 = 0; k0 < K; k0 += 64) {
        #pragma unroll
        for (int rr = 0; rr < 2; rr++) {
            int row = rbase + rr * 32;
            int gm = m0 + row;
            frag8 av = {0, 0, 0, 0, 0, 0, 0, 0};
            if (gm < M) av = *(const frag8*)(A + (size_t)gm * K + k0 + chunk * 8);
            *(frag8*)&As[ks_s][q_s][row][0] = av;
            frag8 wv = *(const frag8*)(W + (size_t)(n0 + row) * K + k0 + chunk * 8);
            *(frag8*)&Bs[ks_s][q_s][row][0] = wv;
        }
        __syncthreads();
        #pragma unroll
        for (int ks = 0; ks < 2; ks++) {
            frag8 a0 = *(const frag8*)&As[ks][quad][wm * 32 + nlo][0];
            frag8 a1 = *(const frag8*)&As[ks][quad][wm * 32 + 16 + nlo][0];
            frag8 b0 = *(const frag8*)&Bs[ks][quad][wn * 32 + nlo][0];
            frag8 b1 = *(const frag8*)&Bs[ks][quad][wn * 32 + 16 + nlo][0];
            acc[0][0] = __builtin_amdgcn_mfma_f32_16x16x32_bf16(a0, b0, acc[0][0], 0, 0, 0);
            acc[0][1] = __builtin_amdgcn_mfma_f32_16x16x32_bf16(a0, b1, acc[0][1], 0, 0, 0);
            acc[1][0] = __builtin_amdgcn_mfma_f32_16x16x32_bf16(a1, b0, acc[1][0], 0, 0, 0);
            acc[1][1] = __builtin_amdgcn_mfma_f32_16x16x32_bf16(a1, b1, acc[1][1], 0, 0, 0);
        }
        __syncthreads();
    }

    #pragma unroll
    for (int mi = 0; mi < 2; mi++) {
        #pragma unroll
        for (int nf = 0; nf < 2; nf++) {
            int col = n0 + wn * 32 + nf * 16 + nlo;
            float bcol = (mode >= 1) ? bias[col] : 0.f;
            float gs = 1.f;
            if (mode == 2 && gvec) gs = gvec[col];
            #pragma unroll
            for (int r = 0; r < 4; r++) {
                int row = m0 + wm * 32 + mi * 16 + quad * 4 + r;
                if (row >= M) continue;
                float v = acc[mi][nf][r] + bcol;
                if (mode == 1) v = 0.5f * v * (1.f + erff(v * 0.70710678118654752f));
                if (mode == 2) {
                    Cf[(size_t)row * Np + col] = resid[(size_t)row * Np + col] + gs * v;
                } else {
                    Cb[(size_t)row * Np + col] = f2bf(v);
                }
            }
        }
    }
}

// ------------------------------------------------------------------
// MFMA flash attention (no rel). qkv bf16 fused buffer pitch QP.
// Output ab bf16 pitch DIM. Block = (qgroup of 64, h, b), 256 thr.
// ------------------------------------------------------------------
__global__ __launch_bounds__(256) void attn_mfma_kernel(
        const short* __restrict__ qkv, const float* __restrict__ maskv,
        short* __restrict__ ob, int Nseq) {
    __shared__ short kf[18][64][8];
    __shared__ short vf[9][2][64][8];
    __shared__ short pbuf[4][16][40];
    __shared__ float ms[320];

    int tid = threadIdx.x;
    int w = tid >> 6, lane = tid & 63;
    int n = lane & 15, quad = lane >> 4;
    int qg = blockIdx.x, h = blockIdx.y, b = blockIdx.z;
    size_t rowB = (size_t)(b * Nseq);

    for (int j = tid; j < 320; j += 256)
        ms[j] = (j < Nseq) ? maskv[b * Nseq + j] : 0.f;

    {
        int c0 = (tid & 3) * 8;
        for (int j = tid >> 2; j < 288; j += 64) {
            frag8 kk = {0, 0, 0, 0, 0, 0, 0, 0};
            frag8 vv = {0, 0, 0, 0, 0, 0, 0, 0};
            if (j < Nseq) {
                const short* base = qkv + (rowB + j) * QP + h * HD + c0;
                kk = *(const frag8*)(base + 384);
                vv = *(const frag8*)(base + 768);
            }
            *(frag8*)&kf[j >> 4][(c0 >> 3) * 16 + (j & 15)][0] = kk;
            #pragma unroll
            for (int e = 0; e < 8; e++) {
                int c = c0 + e;
                vf[j >> 5][c >> 4][((j & 31) >> 3) * 16 + (c & 15)][j & 7] = vv[e];
            }
        }
    }

    int i0 = qg * 64 + w * 16;
    frag8 qa = {0, 0, 0, 0, 0, 0, 0, 0};
    {
        int i = i0 + n;
        if (i < Nseq) qa = *(const frag8*)(qkv + (rowB + i) * QP + h * HD + quad * 8);
    }
    __syncthreads();

    float msq[4];
    #pragma unroll
    for (int r = 0; r < 4; r++) msq[r] = ms[i0 + quad * 4 + r];

    float mrow[4], lsum[4];
    #pragma unroll
    for (int r = 0; r < 4; r++) { mrow[r] = -3.0e38f; lsum[r] = 0.f; }
    f32x4 oacc0 = {0.f, 0.f, 0.f, 0.f}, oacc1 = {0.f, 0.f, 0.f, 0.f};

    for (int jb = 0; jb < 9; jb++) {
        frag8 kb0 = *(const frag8*)&kf[2 * jb][lane][0];
        frag8 kb1 = *(const frag8*)&kf[2 * jb + 1][lane][0];
        f32x4 z = {0.f, 0.f, 0.f, 0.f};
        f32x4 s0 = __builtin_amdgcn_mfma_f32_16x16x32_bf16(qa, kb0, z, 0, 0, 0);
        f32x4 s1 = __builtin_amdgcn_mfma_f32_16x16x32_bf16(qa, kb1, z, 0, 0, 0);

        int j0 = jb * 32 + n;
        int j1 = j0 + 16;
        float mj0 = ms[j0], mj1 = ms[j1];
        float pad0 = (j0 < Nseq) ? 0.f : -1e9f;
        float pad1 = (j1 < Nseq) ? 0.f : -1e9f;

        #pragma unroll
        for (int r = 0; r < 4; r++) {
            float mi = msq[r];
            float b0 = ((fmaxf(mi, mj0) < 0.f) ? 0.f : fminf(mi, mj0)) + pad0;
            float b1 = ((fmaxf(mi, mj1) < 0.f) ? 0.f : fminf(mi, mj1)) + pad1;
            float v0 = s0[r] * SCALE + b0;
            float v1 = s1[r] * SCALE + b1;
            float rm = fmaxf(v0, v1);
            rm = fmaxf(rm, __shfl_xor(rm, 1));
            rm = fmaxf(rm, __shfl_xor(rm, 2));
            rm = fmaxf(rm, __shfl_xor(rm, 4));
            rm = fmaxf(rm, __shfl_xor(rm, 8));
            float mn = fmaxf(mrow[r], rm);
            float alpha = __expf(mrow[r] - mn);
            mrow[r] = mn;
            float p0 = __expf(v0 - mn);
            float p1 = __expf(v1 - mn);
            float ps = p0 + p1;
            ps += __shfl_xor(ps, 1);
            ps += __shfl_xor(ps, 2);
            ps += __shfl_xor(ps, 4);
            ps += __shfl_xor(ps, 8);
            lsum[r] = lsum[r] * alpha + ps;
            oacc0[r] *= alpha;
            oacc1[r] *= alpha;
            pbuf[w][quad * 4 + r][n]      = f2bf(p0);
            pbuf[w][quad * 4 + r][n + 16] = f2bf(p1);
        }
        __syncthreads();
        frag8 pa = *(const frag8*)&pbuf[w][n][quad * 8];
        frag8 vb0 = *(const frag8*)&vf[jb][0][lane][0];
        frag8 vb1 = *(const frag8*)&vf[jb][1][lane][0];
        oacc0 = __builtin_amdgcn_mfma_f32_16x16x32_bf16(pa, vb0, oacc0, 0, 0, 0);
        oacc1 = __builtin_amdgcn_mfma_f32_16x16x32_bf16(pa, vb1, oacc1, 0, 0, 0);
        __syncthreads();
    }

    #pragma unroll
    for (int r = 0; r < 4; r++) {
        int i = i0 + quad * 4 + r;
        if (i < Nseq) {
            float invl = 1.f / lsum[r];
            ob[(rowB + i) * DIM + h * HD + n]      = f2bf(oacc0[r] * invl);
            ob[(rowB + i) * DIM + h * HD + 16 + n] = f2bf(oacc1[r] * invl);
        }
    }
}

// ------------------------------------------------------------------
// fp32 attention with rel bias (layer 0): bf16 qkv in, bf16 ab out
// ------------------------------------------------------------------
#define KP 260
#define VP 33
__global__ __launch_bounds__(512) void attn_rel_kernel(
        const short* __restrict__ qkv, const float* __restrict__ relb,
        const float* __restrict__ maskv, short* __restrict__ ob,
        int Nseq) {
    __shared__ float kT[32 * KP];
    __shared__ float vB[260 * VP];
    __shared__ float sc[32][KP];
    __shared__ float qs4[32][32];
    __shared__ float qsT[32][32];
    __shared__ float ms[288];

    int tid = threadIdx.x;
    int w = tid >> 6, l = tid & 63;
    int half = blockIdx.x, h = blockIdx.y, b = blockIdx.z;
    size_t rowB = (size_t)(b * Nseq);

    for (int j = tid; j < 288; j += 512)
        ms[j] = (j < Nseq) ? maskv[b * Nseq + j] : 0.f;

    {
        int q8 = tid & 3, r = tid >> 2;
        for (int j = r; j < Nseq; j += 128) {
            const short* base = qkv + (rowB + j) * QP + h * HD + q8 * 8;
            frag8 kk = *(const frag8*)(base + 384);
            frag8 vv = *(const frag8*)(base + 768);
            #pragma unroll
            for (int e = 0; e < 8; e++) {
                kT[(q8 * 8 + e) * KP + j] = bf2f(kk[e]);
                vB[j * VP + q8 * 8 + e]   = bf2f(vv[e]);
            }
        }
        if (tid < 128) {
            int cc = tid >> 2, jj = 256 + (tid & 3);
            if (jj >= Nseq) kT[cc * KP + jj] = 0.f;
        }
        for (int t = tid; t < 132; t += 512) {
            int row = 256 + t / VP, cc = t % VP;
            if (row < 260 && row >= Nseq) vB[row * VP + cc] = 0.f;
        }
    }

    int nch = (Nseq + 31) / 32;
    int c0 = (half == 0) ? 0 : (nch + 1) / 2;
    int c1 = (half == 0) ? (nch + 1) / 2 : nch;

    for (int chunk = c0; chunk < c1; chunk++) {
        int i0 = chunk * 32;
        __syncthreads();

        if (tid < 128) {
            int qq = tid >> 2, cb = (tid & 3) * 8;
            int i = i0 + qq;
            frag8 qv = {0, 0, 0, 0, 0, 0, 0, 0};
            if (i < Nseq) qv = *(const frag8*)(qkv + (rowB + i) * QP + h * HD + cb);
            #pragma unroll
            for (int e = 0; e < 8; e++) {
                float v = bf2f(qv[e]) * SCALE;
                qs4[cb + e][qq] = v;
                qsT[qq][cb + e] = v;
            }
        }
        __syncthreads();

        {
            float s[4][4];
            #pragma unroll
            for (int q = 0; q < 4; q++)
                #pragma unroll
                for (int t = 0; t < 4; t++) s[q][t] = 0.f;
            int j0 = 4 * l;
            #pragma unroll 8
            for (int c = 0; c < 32; c++) {
                float4 kq = *(const float4*)&kT[c * KP + j0];
                float4 q4 = *(const float4*)&qs4[c][4 * w];
                s[0][0] += q4.x * kq.x; s[0][1] += q4.x * kq.y; s[0][2] += q4.x * kq.z; s[0][3] += q4.x * kq.w;
                s[1][0] += q4.y * kq.x; s[1][1] += q4.y * kq.y; s[1][2] += q4.y * kq.z; s[1][3] += q4.y * kq.w;
                s[2][0] += q4.z * kq.x; s[2][1] += q4.z * kq.y; s[2][2] += q4.z * kq.z; s[2][3] += q4.z * kq.w;
                s[3][0] += q4.w * kq.x; s[3][1] += q4.w * kq.y; s[3][2] += q4.w * kq.z; s[3][3] += q4.w * kq.w;
            }
            #pragma unroll
            for (int q = 0; q < 4; q++) {
                int i = i0 + 4 * w + q;
                float qr[32];
                #pragma unroll
                for (int c4 = 0; c4 < 8; c4++) {
                    float4 t4 = *(const float4*)&qsT[4 * w + q][c4 * 4];
                    qr[4 * c4] = t4.x; qr[4 * c4 + 1] = t4.y;
                    qr[4 * c4 + 2] = t4.z; qr[4 * c4 + 3] = t4.w;
                }
                const float* rbase = relb + (((size_t)b * N1 + i) * N1 + j0) * HD;
                #pragma unroll
                for (int jj = 0; jj < 4; jj++) {
                    float a = 0.f;
                    #pragma unroll
                    for (int c4 = 0; c4 < 8; c4++) {
                        float4 rv = *(const float4*)(rbase + jj * HD + c4 * 4);
                        a += qr[4 * c4] * rv.x + qr[4 * c4 + 1] * rv.y
                           + qr[4 * c4 + 2] * rv.z + qr[4 * c4 + 3] * rv.w;
                    }
                    s[q][jj] += a;
                }
            }
            #pragma unroll
            for (int q = 0; q < 4; q++) {
                int i = i0 + 4 * w + q;
                float mi = ms[i];
                float4 o4;
                float mj, mn, mx;
                mj = ms[j0 + 0]; mn = fminf(mi, mj); mx = fmaxf(mi, mj);
                o4.x = s[q][0] + ((mx < 0.f) ? 0.f : mn);
                mj = ms[j0 + 1]; mn = fminf(mi, mj); mx = fmaxf(mi, mj);
                o4.y = s[q][1] + ((mx < 0.f) ? 0.f : mn);
                mj = ms[j0 + 2]; mn = fminf(mi, mj); mx = fmaxf(mi, mj);
                o4.z = s[q][2] + ((mx < 0.f) ? 0.f : mn);
                mj = ms[j0 + 3]; mn = fminf(mi, mj); mx = fmaxf(mi, mj);
                o4.w = s[q][3] + ((mx < 0.f) ? 0.f : mn);
                *(float4*)&sc[4 * w + q][j0] = o4;
            }
        }
        __syncthreads();

        float inv[4];
        #pragma unroll
        for (int q = 0; q < 4; q++) {
            int qq = 4 * w + q;
            float4 sv = *(const float4*)&sc[qq][4 * l];
            float lm = fmaxf(fmaxf(sv.x, sv.y), fmaxf(sv.z, sv.w));
            #pragma unroll
            for (int o = 32; o; o >>= 1) lm = fmaxf(lm, __shfl_xor(lm, o, 64));
            float4 ev;
            ev.x = expf(sv.x - lm); ev.y = expf(sv.y - lm);
            ev.z = expf(sv.z - lm); ev.w = expf(sv.w - lm);
            float ls = ev.x + ev.y + ev.z + ev.w;
            #pragma unroll
            for (int o = 32; o; o >>= 1) ls += __shfl_xor(ls, o, 64);
            *(float4*)&sc[qq][4 * l] = ev;
            inv[q] = 1.f / ls;
        }
        __syncthreads();

        {
            int c = l & 31, h2 = l >> 5;
            float acc[4] = {0.f, 0.f, 0.f, 0.f};
            for (int j0 = 4 * h2; j0 < 256; j0 += 8) {
                float v0 = vB[(j0 + 0) * VP + c];
                float v1 = vB[(j0 + 1) * VP + c];
                float v2 = vB[(j0 + 2) * VP + c];
                float v3 = vB[(j0 + 3) * VP + c];
                #pragma unroll
                for (int q = 0; q < 4; q++) {
                    float4 pv = *(const float4*)&sc[4 * w + q][j0];
                    int i = i0 + 4 * w + q;
                    const float* rr = relb + (((size_t)b * N1 + i) * N1 + j0) * HD + c;
                    acc[q] += pv.x * (v0 + rr[0]) + pv.y * (v1 + rr[HD])
                            + pv.z * (v2 + rr[2 * HD]) + pv.w * (v3 + rr[3 * HD]);
                }
            }
            #pragma unroll
            for (int q = 0; q < 4; q++) {
                float t = __shfl_down(acc[q], 32, 64);
                acc[q] += t;
            }
            if (l < 32) {
                #pragma unroll
                for (int q = 0; q < 4; q++) {
                    int i = i0 + 4 * w + q;
                    if (i < Nseq)
                        ob[(rowB + i) * DIM + h * HD + c] = f2bf(acc[q] * inv[q]);
                }
            }
        }
    }
}

// ------------------------------------------------------------------
__global__ __launch_bounds__(256) void concat_kernel(
        const float* __restrict__ xa, const float* __restrict__ clsw,
        const float* __restrict__ mask, float* __restrict__ xb,
        float* __restrict__ m2) {
    int idx = blockIdx.x * 256 + threadIdx.x;
    const int total = BATCH * N2 * DIM;
    if (idx < total) {
        int c = idx % DIM;
        int tokb = idx / DIM;
        int p = tokb % N2, b = tokb / N2;
        xb[idx] = (p == 0) ? clsw[c] : xa[((size_t)(b * N1) + p - 1) * DIM + c];
    }
    if (idx < BATCH * N2) {
        int p = idx % N2, b = idx / N2;
        m2[idx] = (p == 0) ? 0.f : mask[b * N1 + p - 1];
    }
}

__global__ __launch_bounds__(64) void head_kernel(
        const float* __restrict__ xb, const float* __restrict__ ow,
        const float* __restrict__ obv, float* __restrict__ out) {
    int blk = blockIdx.x;
    int b = blk / 3, o = blk % 3;
    int lane = threadIdx.x;
    const float* xr = xb + (size_t)(b * N2) * DIM;
    const float* wr = ow + o * DIM;
    float s = 0.f;
    for (int c = lane; c < DIM; c += 64) s += xr[c] * wr[c];
    for (int off = 32; off; off >>= 1) s += __shfl_down(s, off, 64);
    if (!lane) out[blk] = s + obv[o];
}

// ------------------------------------------------------------------
extern "C" void kernel_launch(void* const* d_in, const int* in_sizes, int n_in,
                              void* d_out, int out_size, void* d_ws, size_t ws_size,
                              hipStream_t stream) {
    (void)in_sizes; (void)n_in; (void)out_size; (void)ws_size;
    const float* X       = (const float*)d_in[0];
    const float* X0      = (const float*)d_in[1];
    const float* MSK     = (const float*)d_in[2];
    const float* RW1     = (const float*)d_in[3];
    const float* RB1     = (const float*)d_in[4];
    const float* RWP     = (const float*)d_in[5];
    const float* RBP     = (const float*)d_in[6];
    const float* SW_LN1G = (const float*)d_in[7];
    const float* SW_LN1B = (const float*)d_in[8];
    const float* SW_LN2G = (const float*)d_in[9];
    const float* SW_LN2B = (const float*)d_in[10];
    const float* SW_WQ   = (const float*)d_in[11];
    const float* SW_WK   = (const float*)d_in[12];
    const float* SW_WV   = (const float*)d_in[13];
    const float* SW_WO   = (const float*)d_in[14];
    const float* SW_BO   = (const float*)d_in[15];
    const float* SW_W1   = (const float*)d_in[16];
    const float* SW_B1   = (const float*)d_in[17];
    const float* SW_W2   = (const float*)d_in[18];
    const float* SW_B2   = (const float*)d_in[19];
    const float* BL_LN1G = (const float*)d_in[20];
    const float* BL_LN1B = (const float*)d_in[21];
    const float* BL_LN2G = (const float*)d_in[22];
    const float* BL_LN2B = (const float*)d_in[23];
    const float* BL_WQ   = (const float*)d_in[24];
    const float* BL_WK   = (const float*)d_in[25];
    const float* BL_WV   = (const float*)d_in[26];
    const float* BL_WO   = (const float*)d_in[27];
    const float* BL_BO   = (const float*)d_in[28];
    const float* BL_W1   = (const float*)d_in[29];
    const float* BL_B1   = (const float*)d_in[30];
    const float* BL_W2   = (const float*)d_in[31];
    const float* BL_B2   = (const float*)d_in[32];
    const float* BL_G1   = (const float*)d_in[33];
    const float* BL_G2   = (const float*)d_in[34];
    const float* CLSW    = (const float*)d_in[35];
    const float* OUTW    = (const float*)d_in[36];
    const float* OUTB    = (const float*)d_in[37];

    const int T1 = BATCH * N1;   // 2048
    const int T2 = BATCH * N2;   // 2056
    const size_t RELSZ = (size_t)BATCH * N1 * N1 * HD;

    float* ws  = (float*)d_ws;
    float* rel = ws;
    float* xa  = rel + RELSZ;
    float* xb  = xa + (size_t)T1 * DIM;
    float* m2  = xb + (size_t)T2 * DIM;
    short* sbase = (short*)(m2 + 2064);
    short* xn   = sbase;
    short* qkv  = xn  + (size_t)T2 * DIM;
    short* ab   = qkv + (size_t)T2 * QP;
    short* hb   = ab  + (size_t)T2 * DIM;
    short* cw_qkv_sw = hb + (size_t)T2 * MLP_H;
    short* cw_qkv_bl = cw_qkv_sw + (size_t)4  * QP * DIM;
    short* cw_wo_sw  = cw_qkv_bl + (size_t)12 * QP * DIM;
    short* cw_wo_bl  = cw_wo_sw  + (size_t)4  * DIM * DIM;
    short* cw_w1_sw  = cw_wo_bl  + (size_t)12 * DIM * DIM;
    short* cw_w1_bl  = cw_w1_sw  + (size_t)4  * MLP_H * DIM;
    short* cw_w2_sw  = cw_w1_bl  + (size_t)12 * MLP_H * DIM;
    short* cw_w2_bl  = cw_w2_sw  + (size_t)4  * DIM * MLP_H;

    // ---- weight conversion ----
    conv_qkv_kernel<<<(4 * QP * DIM / 4 + 255) / 256, 256, 0, stream>>>(SW_WQ, SW_WK, SW_WV, cw_qkv_sw, 4);
    conv_qkv_kernel<<<(12 * QP * DIM / 4 + 255) / 256, 256, 0, stream>>>(BL_WQ, BL_WK, BL_WV, cw_qkv_bl, 12);
    conv_kernel<<<(4 * DIM * DIM / 4 + 255) / 256, 256, 0, stream>>>(SW_WO, cw_wo_sw, 4 * DIM * DIM);
    conv_kernel<<<(12 * DIM * DIM / 4 + 255) / 256, 256, 0, stream>>>(BL_WO, cw_wo_bl, 12 * DIM * DIM);
    conv_kernel<<<(4 * MLP_H * DIM / 4 + 255) / 256, 256, 0, stream>>>(SW_W1, cw_w1_sw, 4 * MLP_H * DIM);
    conv_kernel<<<(12 * MLP_H * DIM / 4 + 255) / 256, 256, 0, stream>>>(BL_W1, cw_w1_bl, 12 * MLP_H * DIM);
    conv_kernel<<<(4 * DIM * MLP_H / 4 + 255) / 256, 256, 0, stream>>>(SW_W2, cw_w2_sw, 4 * DIM * MLP_H);
    conv_kernel<<<(12 * DIM * MLP_H / 4 + 255) / 256, 256, 0, stream>>>(BL_W2, cw_w2_bl, 12 * DIM * MLP_H);

    rel_kernel<<<BATCH * N1 * N1 / 256, 256, 0, stream>>>(X0, RW1, RB1, RWP, RBP, rel);
    hipMemcpyAsync(xa, X, sizeof(float) * T1 * DIM, hipMemcpyDeviceToDevice, stream);

    // ---------------- phase 1: sw layers (N=256) ----------------
    dim3 gQ1(QP / 64, T1 / 64);                 // (18, 32)
    dim3 gP1(DIM / 64, T1 / 64);                // (6, 32)
    dim3 gM1(MLP_H / 64, T1 / 64);              // (24, 32)
    dim3 gRel(2, HEADS, BATCH);
    dim3 gF1(4, HEADS, BATCH);
    for (int l = 0; l < 4; l++) {
        const short* wqkv = cw_qkv_sw + (size_t)l * QP * DIM;
        const short* wo = cw_wo_sw + (size_t)l * DIM * DIM;
        const short* w1 = cw_w1_sw + (size_t)l * MLP_H * DIM;
        const short* w2 = cw_w2_sw + (size_t)l * DIM * MLP_H;
        const float* bo = SW_BO + (size_t)l * DIM;
        const float* b1 = SW_B1 + (size_t)l * MLP_H;
        const float* b2 = SW_B2 + (size_t)l * DIM;

        ln_kernel<<<T1, 128, 0, stream>>>(xa, SW_LN1G + l * DIM, SW_LN1B + l * DIM, xn);
        gemm_bf16_kernel<<<gQ1, 256, 0, stream>>>(xn, wqkv, nullptr, nullptr, nullptr,
                                                  nullptr, qkv, T1, QP, DIM, 0);
        if (l == 0)
            attn_rel_kernel<<<gRel, 512, 0, stream>>>(qkv, rel, MSK, ab, N1);
        else
            attn_mfma_kernel<<<gF1, 256, 0, stream>>>(qkv, MSK, ab, N1);
        gemm_bf16_kernel<<<gP1, 256, 0, stream>>>(ab, wo, bo, xa, nullptr,
                                                  xa, nullptr, T1, DIM, DIM, 2);
        ln_kernel<<<T1, 128, 0, stream>>>(xa, SW_LN2G + l * DIM, SW_LN2B + l * DIM, xn);
        gemm_bf16_kernel<<<gM1, 256, 0, stream>>>(xn, w1, b1, nullptr, nullptr,
                                                  nullptr, hb, T1, MLP_H, DIM, 1);
        gemm_bf16_kernel<<<gP1, 256, 0, stream>>>(hb, w2, b2, xa, nullptr,
                                                  xa, nullptr, T1, DIM, MLP_H, 2);
    }

    // ---------------- concat cls ----------------
    concat_kernel<<<(BATCH * N2 * DIM + 255) / 256, 256, 0, stream>>>(xa, CLSW, MSK, xb, m2);

    // ---------------- phase 2: bl layers (N=257) ----------------
    int MB2 = (T2 + 63) / 64;                   // 33
    dim3 gQ2(QP / 64, MB2);
    dim3 gP2(DIM / 64, MB2);
    dim3 gM2(MLP_H / 64, MB2);
    dim3 gF2(5, HEADS, BATCH);
    for (int l = 0; l < 12; l++) {
        const short* wqkv = cw_qkv_bl + (size_t)l * QP * DIM;
        const short* wo = cw_wo_bl + (size_t)l * DIM * DIM;
        const short* w1 = cw_w1_bl + (size_t)l * MLP_H * DIM;
        const short* w2 = cw_w2_bl + (size_t)l * DIM * MLP_H;
        const float* bo = BL_BO + (size_t)l * DIM;
        const float* b1 = BL_B1 + (size_t)l * MLP_H;
        const float* b2 = BL_B2 + (size_t)l * DIM;
        const float* g1 = BL_G1 + (size_t)l * DIM;
        const float* g2 = BL_G2 + (size_t)l * DIM;

        ln_kernel<<<T2, 128, 0, stream>>>(xb, BL_LN1G + l * DIM, BL_LN1B + l * DIM, xn);
        gemm_bf16_kernel<<<gQ2, 256, 0, stream>>>(xn, wqkv, nullptr, nullptr, nullptr,
                                                  nullptr, qkv, T2, QP, DIM, 0);
        attn_mfma_kernel<<<gF2, 256, 0, stream>>>(qkv, m2, ab, N2);
        gemm_bf16_kernel<<<gP2, 256, 0, stream>>>(ab, wo, bo, xb, g1,
                                                  xb, nullptr, T2, DIM, DIM, 2);
        ln_kernel<<<T2, 128, 0, stream>>>(xb, BL_LN2G + l * DIM, BL_LN2B + l * DIM, xn);
        gemm_bf16_kernel<<<gM2, 256, 0, stream>>>(xn, w1, b1, nullptr, nullptr,
                                                  nullptr, hb, T2, MLP_H, DIM, 1);
        gemm_bf16_kernel<<<gP2, 256, 0, stream>>>(hb, w2, b2, xb, g2,
                                                  xb, nullptr, T2, DIM, MLP_H, 2);
    }

    // ---------------- head ----------------
    head_kernel<<<BATCH * 3, 64, 0, stream>>>(xb, OUTW, OUTB, (float*)d_out);
}

// Round 7
// 2006.082 us; speedup vs baseline: 2.7523x; 1.0562x over previous
//
#include <hip/hip_runtime.h>
#include <hip/hip_bf16.h>
#include <math.h>

#define DIM 384
#define HEADS 12
#define HD 32
#define MLP_H 1536
#define BATCH 8
#define N1 256
#define N2 257
#define QP 1152          // fused qkv row pitch (shorts)
#define SCALE 0.17677669529663687f
#define TIME_SCALE 18.0f

typedef __attribute__((ext_vector_type(8))) short frag8;
typedef __attribute__((ext_vector_type(4))) float f32x4;

__device__ inline short f2bf(float x) {
    __hip_bfloat16 h = __float2bfloat16(x);
    short s;
    __builtin_memcpy(&s, &h, 2);
    return s;
}
__device__ inline float bf2f(short s) {
    unsigned u = ((unsigned)(unsigned short)s) << 16;
    float f;
    __builtin_memcpy(&f, &u, 4);
    return f;
}

// ------------------------------------------------------------------
// weight conversion: fp32 -> bf16 (plain)
// ------------------------------------------------------------------
__global__ __launch_bounds__(256) void conv_kernel(
        const float* __restrict__ in, short* __restrict__ out, int n) {
    int i = (blockIdx.x * 256 + threadIdx.x) * 4;
    if (i >= n) return;
    float4 v = *(const float4*)(in + i);
    out[i]     = f2bf(v.x);
    out[i + 1] = f2bf(v.y);
    out[i + 2] = f2bf(v.z);
    out[i + 3] = f2bf(v.w);
}

// gather-convert: per layer pack [wq;wk;wv] -> (L,1152,384) bf16
__global__ __launch_bounds__(256) void conv_qkv_kernel(
        const float* __restrict__ wq, const float* __restrict__ wk,
        const float* __restrict__ wv, short* __restrict__ out, int L) {
    size_t idx = ((size_t)blockIdx.x * 256 + threadIdx.x) * 4;
    size_t total = (size_t)L * QP * DIM;
    if (idx >= total) return;
    size_t k = idx % DIM;
    size_t row = idx / DIM;
    size_t r = row % QP;
    size_t l = row / QP;
    int which = (int)(r / DIM);
    int rr = (int)(r % DIM);
    const float* src = ((which == 0) ? wq : (which == 1) ? wk : wv)
                     + (l * DIM + rr) * DIM + k;
    float4 v = *(const float4*)src;
    out[idx]     = f2bf(v.x);
    out[idx + 1] = f2bf(v.y);
    out[idx + 2] = f2bf(v.z);
    out[idx + 3] = f2bf(v.w);
}

// ------------------------------------------------------------------
// rel bias -> bf16
// ------------------------------------------------------------------
__global__ __launch_bounds__(256) void rel_kernel(
        const float* __restrict__ x0, const float* __restrict__ w1d,
        const float* __restrict__ b1d, const float* __restrict__ wp,
        const float* __restrict__ bp, short* __restrict__ rel) {
    __shared__ float swp[HD * HD];
    __shared__ float sbp[HD];
    __shared__ float sw1[8];
    __shared__ float sb1;
    __shared__ float sfreq[16];
    int tid = threadIdx.x;
    for (int i = tid; i < HD * HD; i += 256) swp[i] = wp[i];
    if (tid < HD) sbp[tid] = bp[tid];
    if (tid < 8) sw1[tid] = w1d[tid];
    if (tid == 0) sb1 = b1d[0];
    if (tid < 16) sfreq[tid] = expf(-(float)tid * 0.5756462732485114f);
    __syncthreads();

    int gid = blockIdx.x * 256 + tid;
    int j  = gid & (N1 - 1);
    int bi = gid >> 8;
    int i  = bi & (N1 - 1);
    int b  = bi >> 8;

    const float* pi = x0 + (size_t)(b * N1 + i) * 4;
    const float* pj = x0 + (size_t)(b * N1 + j) * 4;
    float dx = pi[0] - pj[0], dy = pi[1] - pj[1], dz = pi[2] - pj[2];
    float dt = pi[3] - pj[3] * TIME_SCALE;
    float dx2 = dx * dx, dy2 = dy * dy, dz2 = dz * dz, dt2 = dt * dt;
    float ds2 = dx2 + dy2 + dz2 - dt2;
    float d = copysignf(sqrtf(fabsf(ds2)), ds2);
    d += dx * sw1[0] + dy * sw1[1] + dz * sw1[2] + dt * sw1[3]
       + dx2 * sw1[4] + dy2 * sw1[5] + dz2 * sw1[6] + dt2 * sw1[7] + sb1;
    d = fminf(fmaxf(d, -4.f), 4.f) * 1024.f;

    float emb[32];
    #pragma unroll
    for (int k = 0; k < 16; k++) {
        float s, c;
        sincosf(d * sfreq[k], &s, &c);
        emb[k] = s; emb[16 + k] = c;
    }
    short* out = rel + (size_t)gid * HD;
    #pragma unroll 4
    for (int c = 0; c < HD; c++) {
        float a = sbp[c];
        #pragma unroll
        for (int k = 0; k < 32; k++) a += emb[k] * swp[c * 32 + k];
        out[c] = f2bf(a);
    }
}

// ------------------------------------------------------------------
// LayerNorm: fp32 in -> bf16 out
// ------------------------------------------------------------------
__global__ __launch_bounds__(128) void ln_kernel(
        const float* __restrict__ x, const float* __restrict__ g,
        const float* __restrict__ b, short* __restrict__ y) {
    int r = blockIdx.x;
    int t = threadIdx.x;
    const float* xr = x + (size_t)r * DIM;
    float v0 = xr[t], v1 = xr[t + 128], v2 = xr[t + 256];
    __shared__ float redm[2], redv[2];
    float s = v0 + v1 + v2;
    for (int o = 32; o; o >>= 1) s += __shfl_down(s, o, 64);
    int lane = t & 63, wid = t >> 6;
    if (!lane) redm[wid] = s;
    __syncthreads();
    float mean = (redm[0] + redm[1]) * (1.f / DIM);
    float d0 = v0 - mean, d1 = v1 - mean, d2 = v2 - mean;
    float s2 = d0 * d0 + d1 * d1 + d2 * d2;
    for (int o = 32; o; o >>= 1) s2 += __shfl_down(s2, o, 64);
    if (!lane) redv[wid] = s2;
    __syncthreads();
    float var = (redv[0] + redv[1]) * (1.f / DIM);
    float rs = rsqrtf(var + 1e-5f);
    short* yr = y + (size_t)r * DIM;
    yr[t]       = f2bf(d0 * rs * g[t]       + b[t]);
    yr[t + 128] = f2bf(d1 * rs * g[t + 128] + b[t + 128]);
    yr[t + 256] = f2bf(d2 * rs * g[t + 256] + b[t + 256]);
}

// ------------------------------------------------------------------
// bf16 MFMA GEMM (verified R6)
// ------------------------------------------------------------------
__global__ __launch_bounds__(256) void gemm_bf16_kernel(
        const short* __restrict__ A, const short* __restrict__ W,
        const float* __restrict__ bias, const float* __restrict__ resid,
        const float* __restrict__ gvec, float* __restrict__ Cf,
        short* __restrict__ Cb, int M, int Np, int K, int mode) {
    __shared__ short As[2][4][64][8];
    __shared__ short Bs[2][4][64][8];
    int tid = threadIdx.x;
    int w = tid >> 6, lane = tid & 63;
    int nlo = lane & 15, quad = lane >> 4;
    int wm = w >> 1, wn = w & 1;
    int n0 = blockIdx.x * 64, m0 = blockIdx.y * 64;

    f32x4 acc[2][2];
    #pragma unroll
    for (int a = 0; a < 2; a++)
        #pragma unroll
        for (int c = 0; c < 2; c++) acc[a][c] = (f32x4){0.f, 0.f, 0.f, 0.f};

    int chunk = tid & 7, ks_s = chunk >> 2, q_s = chunk & 3;
    int rbase = tid >> 3;

    for (int k0 = 0; k0 < K; k0 += 64) {
        #pragma unroll
        for (int rr = 0; rr < 2; rr++) {
            int row = rbase + rr * 32;
            int gm = m0 + row;
            frag8 av = {0, 0, 0, 0, 0, 0, 0, 0};
            if (gm < M) av = *(const frag8*)(A + (size_t)gm * K + k0 + chunk * 8);
            *(frag8*)&As[ks_s][q_s][row][0] = av;
            frag8 wv = *(const frag8*)(W + (size_t)(n0 + row) * K + k0 + chunk * 8);
            *(frag8*)&Bs[ks_s][q_s][row][0] = wv;
        }
        __syncthreads();
        #pragma unroll
        for (int ks = 0; ks < 2; ks++) {
            frag8 a0 = *(const frag8*)&As[ks][quad][wm * 32 + nlo][0];
            frag8 a1 = *(const frag8*)&As[ks][quad][wm * 32 + 16 + nlo][0];
            frag8 b0 = *(const frag8*)&Bs[ks][quad][wn * 32 + nlo][0];
            frag8 b1 = *(const frag8*)&Bs[ks][quad][wn * 32 + 16 + nlo][0];
            acc[0][0] = __builtin_amdgcn_mfma_f32_16x16x32_bf16(a0, b0, acc[0][0], 0, 0, 0);
            acc[0][1] = __builtin_amdgcn_mfma_f32_16x16x32_bf16(a0, b1, acc[0][1], 0, 0, 0);
            acc[1][0] = __builtin_amdgcn_mfma_f32_16x16x32_bf16(a1, b0, acc[1][0], 0, 0, 0);
            acc[1][1] = __builtin_amdgcn_mfma_f32_16x16x32_bf16(a1, b1, acc[1][1], 0, 0, 0);
        }
        __syncthreads();
    }

    #pragma unroll
    for (int mi = 0; mi < 2; mi++) {
        #pragma unroll
        for (int nf = 0; nf < 2; nf++) {
            int col = n0 + wn * 32 + nf * 16 + nlo;
            float bcol = (mode >= 1) ? bias[col] : 0.f;
            float gs = 1.f;
            if (mode == 2 && gvec) gs = gvec[col];
            #pragma unroll
            for (int r = 0; r < 4; r++) {
                int row = m0 + wm * 32 + mi * 16 + quad * 4 + r;
                if (row >= M) continue;
                float v = acc[mi][nf][r] + bcol;
                if (mode == 1) v = 0.5f * v * (1.f + erff(v * 0.70710678118654752f));
                if (mode == 2) {
                    Cf[(size_t)row * Np + col] = resid[(size_t)row * Np + col] + gs * v;
                } else {
                    Cb[(size_t)row * Np + col] = f2bf(v);
                }
            }
        }
    }
}

// ------------------------------------------------------------------
// MFMA flash attention (no rel) — verified R5/R6
// ------------------------------------------------------------------
__global__ __launch_bounds__(256) void attn_mfma_kernel(
        const short* __restrict__ qkv, const float* __restrict__ maskv,
        short* __restrict__ ob, int Nseq) {
    __shared__ short kf[18][64][8];
    __shared__ short vf[9][2][64][8];
    __shared__ short pbuf[4][16][40];
    __shared__ float ms[320];

    int tid = threadIdx.x;
    int w = tid >> 6, lane = tid & 63;
    int n = lane & 15, quad = lane >> 4;
    int qg = blockIdx.x, h = blockIdx.y, b = blockIdx.z;
    size_t rowB = (size_t)(b * Nseq);

    for (int j = tid; j < 320; j += 256)
        ms[j] = (j < Nseq) ? maskv[b * Nseq + j] : 0.f;

    {
        int c0 = (tid & 3) * 8;
        for (int j = tid >> 2; j < 288; j += 64) {
            frag8 kk = {0, 0, 0, 0, 0, 0, 0, 0};
            frag8 vv = {0, 0, 0, 0, 0, 0, 0, 0};
            if (j < Nseq) {
                const short* base = qkv + (rowB + j) * QP + h * HD + c0;
                kk = *(const frag8*)(base + 384);
                vv = *(const frag8*)(base + 768);
            }
            *(frag8*)&kf[j >> 4][(c0 >> 3) * 16 + (j & 15)][0] = kk;
            #pragma unroll
            for (int e = 0; e < 8; e++) {
                int c = c0 + e;
                vf[j >> 5][c >> 4][((j & 31) >> 3) * 16 + (c & 15)][j & 7] = vv[e];
            }
        }
    }

    int i0 = qg * 64 + w * 16;
    frag8 qa = {0, 0, 0, 0, 0, 0, 0, 0};
    {
        int i = i0 + n;
        if (i < Nseq) qa = *(const frag8*)(qkv + (rowB + i) * QP + h * HD + quad * 8);
    }
    __syncthreads();

    float msq[4];
    #pragma unroll
    for (int r = 0; r < 4; r++) msq[r] = ms[i0 + quad * 4 + r];

    float mrow[4], lsum[4];
    #pragma unroll
    for (int r = 0; r < 4; r++) { mrow[r] = -3.0e38f; lsum[r] = 0.f; }
    f32x4 oacc0 = {0.f, 0.f, 0.f, 0.f}, oacc1 = {0.f, 0.f, 0.f, 0.f};

    for (int jb = 0; jb < 9; jb++) {
        frag8 kb0 = *(const frag8*)&kf[2 * jb][lane][0];
        frag8 kb1 = *(const frag8*)&kf[2 * jb + 1][lane][0];
        f32x4 z = {0.f, 0.f, 0.f, 0.f};
        f32x4 s0 = __builtin_amdgcn_mfma_f32_16x16x32_bf16(qa, kb0, z, 0, 0, 0);
        f32x4 s1 = __builtin_amdgcn_mfma_f32_16x16x32_bf16(qa, kb1, z, 0, 0, 0);

        int j0 = jb * 32 + n;
        int j1 = j0 + 16;
        float mj0 = ms[j0], mj1 = ms[j1];
        float pad0 = (j0 < Nseq) ? 0.f : -1e9f;
        float pad1 = (j1 < Nseq) ? 0.f : -1e9f;

        #pragma unroll
        for (int r = 0; r < 4; r++) {
            float mi = msq[r];
            float b0 = ((fmaxf(mi, mj0) < 0.f) ? 0.f : fminf(mi, mj0)) + pad0;
            float b1 = ((fmaxf(mi, mj1) < 0.f) ? 0.f : fminf(mi, mj1)) + pad1;
            float v0 = s0[r] * SCALE + b0;
            float v1 = s1[r] * SCALE + b1;
            float rm = fmaxf(v0, v1);
            rm = fmaxf(rm, __shfl_xor(rm, 1));
            rm = fmaxf(rm, __shfl_xor(rm, 2));
            rm = fmaxf(rm, __shfl_xor(rm, 4));
            rm = fmaxf(rm, __shfl_xor(rm, 8));
            float mn = fmaxf(mrow[r], rm);
            float alpha = __expf(mrow[r] - mn);
            mrow[r] = mn;
            float p0 = __expf(v0 - mn);
            float p1 = __expf(v1 - mn);
            float ps = p0 + p1;
            ps += __shfl_xor(ps, 1);
            ps += __shfl_xor(ps, 2);
            ps += __shfl_xor(ps, 4);
            ps += __shfl_xor(ps, 8);
            lsum[r] = lsum[r] * alpha + ps;
            oacc0[r] *= alpha;
            oacc1[r] *= alpha;
            pbuf[w][quad * 4 + r][n]      = f2bf(p0);
            pbuf[w][quad * 4 + r][n + 16] = f2bf(p1);
        }
        __syncthreads();
        frag8 pa = *(const frag8*)&pbuf[w][n][quad * 8];
        frag8 vb0 = *(const frag8*)&vf[jb][0][lane][0];
        frag8 vb1 = *(const frag8*)&vf[jb][1][lane][0];
        oacc0 = __builtin_amdgcn_mfma_f32_16x16x32_bf16(pa, vb0, oacc0, 0, 0, 0);
        oacc1 = __builtin_amdgcn_mfma_f32_16x16x32_bf16(pa, vb1, oacc1, 0, 0, 0);
        __syncthreads();
    }

    #pragma unroll
    for (int r = 0; r < 4; r++) {
        int i = i0 + quad * 4 + r;
        if (i < Nseq) {
            float invl = 1.f / lsum[r];
            ob[(rowB + i) * DIM + h * HD + n]      = f2bf(oacc0[r] * invl);
            ob[(rowB + i) * DIM + h * HD + 16 + n] = f2bf(oacc1[r] * invl);
        }
    }
}

// ------------------------------------------------------------------
// MFMA flash attention WITH rel bias (layer 0, Nseq == N1 == 256).
// Same MFMA core; rel contributions added SIMT:
//  - QK-rel: lane (C-layout role) dots q[i,:] (LDS fp32, broadcast)
//    against rel[b,i,j,:] (contiguous bf16 frag8 global loads).
//  - PV-rel: lane role (i=lane&15, c-octet=lane>>4) accumulates
//    sum_j p*rel in regs with online rescale via per-row alpha (LDS),
//    merged into the O accumulator through LDS at store.
// ------------------------------------------------------------------
__global__ __launch_bounds__(256) void attn_rel_mfma_kernel(
        const short* __restrict__ qkv, const short* __restrict__ relb,
        const float* __restrict__ maskv, short* __restrict__ ob) {
    const int Nseq = N1;
    __shared__ short kf[16][64][8];     // 16 KB
    __shared__ short vf[8][2][64][8];   // 16 KB
    __shared__ short pbuf[4][16][40];   // 5 KB
    __shared__ float qrow[4][16][32];   // 8 KB [w][i_loc][c], q*SCALE
    __shared__ float orel[4][16][33];   // 8.4 KB
    __shared__ float alphas[4][16];
    __shared__ float ms[256];

    int tid = threadIdx.x;
    int w = tid >> 6, lane = tid & 63;
    int n = lane & 15, quad = lane >> 4;
    int qg = blockIdx.x, h = blockIdx.y, b = blockIdx.z;
    size_t rowB = (size_t)(b * Nseq);

    if (tid < 256) ms[tid] = maskv[b * Nseq + tid];

    {
        int c0 = (tid & 3) * 8;
        for (int j = tid >> 2; j < 256; j += 64) {
            const short* base = qkv + (rowB + j) * QP + h * HD + c0;
            frag8 kk = *(const frag8*)(base + 384);
            frag8 vv = *(const frag8*)(base + 768);
            *(frag8*)&kf[j >> 4][(c0 >> 3) * 16 + (j & 15)][0] = kk;
            #pragma unroll
            for (int e = 0; e < 8; e++) {
                int c = c0 + e;
                vf[j >> 5][c >> 4][((j & 31) >> 3) * 16 + (c & 15)][j & 7] = vv[e];
            }
        }
    }

    int i0 = qg * 64 + w * 16;
    frag8 qa = *(const frag8*)(qkv + (rowB + i0 + n) * QP + h * HD + quad * 8);
    {   // stage q rows fp32*SCALE: lane covers (i_loc = lane>>2, c8 = (lane&3)*8)
        int il = lane >> 2, c8 = (lane & 3) * 8;
        frag8 qv = *(const frag8*)(qkv + (rowB + i0 + il) * QP + h * HD + c8);
        #pragma unroll
        for (int e = 0; e < 8; e++) qrow[w][il][c8 + e] = bf2f(qv[e]) * SCALE;
    }
    __syncthreads();

    float msq[4];
    #pragma unroll
    for (int r = 0; r < 4; r++) msq[r] = ms[i0 + quad * 4 + r];

    float mrow[4], lsum[4];
    #pragma unroll
    for (int r = 0; r < 4; r++) { mrow[r] = -3.0e38f; lsum[r] = 0.f; }
    f32x4 oacc0 = {0.f, 0.f, 0.f, 0.f}, oacc1 = {0.f, 0.f, 0.f, 0.f};
    float arel[8];
    #pragma unroll
    for (int e = 0; e < 8; e++) arel[e] = 0.f;

    int il = lane & 15, oct = lane >> 4;   // PV-rel role
    const short* relrow = relb + (((size_t)b * N1 + (i0 + il)) * N1) * HD + oct * 8;

    for (int jb = 0; jb < 8; jb++) {
        frag8 kb0 = *(const frag8*)&kf[2 * jb][lane][0];
        frag8 kb1 = *(const frag8*)&kf[2 * jb + 1][lane][0];
        f32x4 z = {0.f, 0.f, 0.f, 0.f};
        f32x4 s0 = __builtin_amdgcn_mfma_f32_16x16x32_bf16(qa, kb0, z, 0, 0, 0);
        f32x4 s1 = __builtin_amdgcn_mfma_f32_16x16x32_bf16(qa, kb1, z, 0, 0, 0);

        int j0 = jb * 32 + n;
        int j1 = j0 + 16;
        float mj0 = ms[j0], mj1 = ms[j1];

        #pragma unroll
        for (int r = 0; r < 4; r++) {
            int i = i0 + quad * 4 + r;
            // QK-rel dots
            const short* r0 = relb + (((size_t)b * N1 + i) * N1 + j0) * HD;
            const short* r1 = relb + (((size_t)b * N1 + i) * N1 + j1) * HD;
            float d0 = 0.f, d1 = 0.f;
            #pragma unroll
            for (int c8 = 0; c8 < 4; c8++) {
                frag8 ra = *(const frag8*)(r0 + c8 * 8);
                frag8 rb_ = *(const frag8*)(r1 + c8 * 8);
                const float* qp = &qrow[w][quad * 4 + r][c8 * 8];
                #pragma unroll
                for (int e = 0; e < 8; e++) {
                    float qv = qp[e];
                    d0 += qv * bf2f(ra[e]);
                    d1 += qv * bf2f(rb_[e]);
                }
            }
            float mi = msq[r];
            float b0 = (fmaxf(mi, mj0) < 0.f) ? 0.f : fminf(mi, mj0);
            float b1 = (fmaxf(mi, mj1) < 0.f) ? 0.f : fminf(mi, mj1);
            float v0 = s0[r] * SCALE + d0 + b0;
            float v1 = s1[r] * SCALE + d1 + b1;
            float rm = fmaxf(v0, v1);
            rm = fmaxf(rm, __shfl_xor(rm, 1));
            rm = fmaxf(rm, __shfl_xor(rm, 2));
            rm = fmaxf(rm, __shfl_xor(rm, 4));
            rm = fmaxf(rm, __shfl_xor(rm, 8));
            float mn = fmaxf(mrow[r], rm);
            float alpha = __expf(mrow[r] - mn);
            mrow[r] = mn;
            float p0 = __expf(v0 - mn);
            float p1 = __expf(v1 - mn);
            float ps = p0 + p1;
            ps += __shfl_xor(ps, 1);
            ps += __shfl_xor(ps, 2);
            ps += __shfl_xor(ps, 4);
            ps += __shfl_xor(ps, 8);
            lsum[r] = lsum[r] * alpha + ps;
            oacc0[r] *= alpha;
            oacc1[r] *= alpha;
            pbuf[w][quad * 4 + r][n]      = f2bf(p0);
            pbuf[w][quad * 4 + r][n + 16] = f2bf(p1);
            if (n == 0) alphas[w][quad * 4 + r] = alpha;
        }
        __syncthreads();
        // PV-rel (register accumulate, online rescale)
        {
            float al = alphas[w][il];
            #pragma unroll
            for (int e = 0; e < 8; e++) arel[e] *= al;
            const short* rb2 = relrow + (size_t)(jb * 32) * HD;
            #pragma unroll 8
            for (int jj = 0; jj < 32; jj++) {
                float p = bf2f(pbuf[w][il][jj]);
                frag8 rv = *(const frag8*)(rb2 + (size_t)jj * HD);
                #pragma unroll
                for (int e = 0; e < 8; e++) arel[e] += p * bf2f(rv[e]);
            }
        }
        frag8 pa = *(const frag8*)&pbuf[w][n][quad * 8];
        frag8 vb0 = *(const frag8*)&vf[jb][0][lane][0];
        frag8 vb1 = *(const frag8*)&vf[jb][1][lane][0];
        oacc0 = __builtin_amdgcn_mfma_f32_16x16x32_bf16(pa, vb0, oacc0, 0, 0, 0);
        oacc1 = __builtin_amdgcn_mfma_f32_16x16x32_bf16(pa, vb1, oacc1, 0, 0, 0);
        __syncthreads();
    }

    // publish PV-rel accumulators, merge, store
    #pragma unroll
    for (int e = 0; e < 8; e++) orel[w][il][oct * 8 + e] = arel[e];
    __syncthreads();

    #pragma unroll
    for (int r = 0; r < 4; r++) {
        int i = i0 + quad * 4 + r;
        float invl = 1.f / lsum[r];
        float o0 = (oacc0[r] + orel[w][quad * 4 + r][n])      * invl;
        float o1 = (oacc1[r] + orel[w][quad * 4 + r][16 + n]) * invl;
        ob[(rowB + i) * DIM + h * HD + n]      = f2bf(o0);
        ob[(rowB + i) * DIM + h * HD + 16 + n] = f2bf(o1);
    }
}

// ------------------------------------------------------------------
__global__ __launch_bounds__(256) void concat_kernel(
        const float* __restrict__ xa, const float* __restrict__ clsw,
        const float* __restrict__ mask, float* __restrict__ xb,
        float* __restrict__ m2) {
    int idx = blockIdx.x * 256 + threadIdx.x;
    const int total = BATCH * N2 * DIM;
    if (idx < total) {
        int c = idx % DIM;
        int tokb = idx / DIM;
        int p = tokb % N2, b = tokb / N2;
        xb[idx] = (p == 0) ? clsw[c] : xa[((size_t)(b * N1) + p - 1) * DIM + c];
    }
    if (idx < BATCH * N2) {
        int p = idx % N2, b = idx / N2;
        m2[idx] = (p == 0) ? 0.f : mask[b * N1 + p - 1];
    }
}

__global__ __launch_bounds__(64) void head_kernel(
        const float* __restrict__ xb, const float* __restrict__ ow,
        const float* __restrict__ obv, float* __restrict__ out) {
    int blk = blockIdx.x;
    int b = blk / 3, o = blk % 3;
    int lane = threadIdx.x;
    const float* xr = xb + (size_t)(b * N2) * DIM;
    const float* wr = ow + o * DIM;
    float s = 0.f;
    for (int c = lane; c < DIM; c += 64) s += xr[c] * wr[c];
    for (int off = 32; off; off >>= 1) s += __shfl_down(s, off, 64);
    if (!lane) out[blk] = s + obv[o];
}

// ------------------------------------------------------------------
extern "C" void kernel_launch(void* const* d_in, const int* in_sizes, int n_in,
                              void* d_out, int out_size, void* d_ws, size_t ws_size,
                              hipStream_t stream) {
    (void)in_sizes; (void)n_in; (void)out_size; (void)ws_size;
    const float* X       = (const float*)d_in[0];
    const float* X0      = (const float*)d_in[1];
    const float* MSK     = (const float*)d_in[2];
    const float* RW1     = (const float*)d_in[3];
    const float* RB1     = (const float*)d_in[4];
    const float* RWP     = (const float*)d_in[5];
    const float* RBP     = (const float*)d_in[6];
    const float* SW_LN1G = (const float*)d_in[7];
    const float* SW_LN1B = (const float*)d_in[8];
    const float* SW_LN2G = (const float*)d_in[9];
    const float* SW_LN2B = (const float*)d_in[10];
    const float* SW_WQ   = (const float*)d_in[11];
    const float* SW_WK   = (const float*)d_in[12];
    const float* SW_WV   = (const float*)d_in[13];
    const float* SW_WO   = (const float*)d_in[14];
    const float* SW_BO   = (const float*)d_in[15];
    const float* SW_W1   = (const float*)d_in[16];
    const float* SW_B1   = (const float*)d_in[17];
    const float* SW_W2   = (const float*)d_in[18];
    const float* SW_B2   = (const float*)d_in[19];
    const float* BL_LN1G = (const float*)d_in[20];
    const float* BL_LN1B = (const float*)d_in[21];
    const float* BL_LN2G = (const float*)d_in[22];
    const float* BL_LN2B = (const float*)d_in[23];
    const float* BL_WQ   = (const float*)d_in[24];
    const float* BL_WK   = (const float*)d_in[25];
    const float* BL_WV   = (const float*)d_in[26];
    const float* BL_WO   = (const float*)d_in[27];
    const float* BL_BO   = (const float*)d_in[28];
    const float* BL_W1   = (const float*)d_in[29];
    const float* BL_B1   = (const float*)d_in[30];
    const float* BL_W2   = (const float*)d_in[31];
    const float* BL_B2   = (const float*)d_in[32];
    const float* BL_G1   = (const float*)d_in[33];
    const float* BL_G2   = (const float*)d_in[34];
    const float* CLSW    = (const float*)d_in[35];
    const float* OUTW    = (const float*)d_in[36];
    const float* OUTB    = (const float*)d_in[37];

    const int T1 = BATCH * N1;   // 2048
    const int T2 = BATCH * N2;   // 2056
    const size_t RELSZ = (size_t)BATCH * N1 * N1 * HD;   // shorts

    short* rel = (short*)d_ws;
    float* xa  = (float*)(rel + RELSZ);
    float* xb  = xa + (size_t)T1 * DIM;
    float* m2  = xb + (size_t)T2 * DIM;
    short* sbase = (short*)(m2 + 2064);
    short* xn   = sbase;
    short* qkv  = xn  + (size_t)T2 * DIM;
    short* ab   = qkv + (size_t)T2 * QP;
    short* hb   = ab  + (size_t)T2 * DIM;
    short* cw_qkv_sw = hb + (size_t)T2 * MLP_H;
    short* cw_qkv_bl = cw_qkv_sw + (size_t)4  * QP * DIM;
    short* cw_wo_sw  = cw_qkv_bl + (size_t)12 * QP * DIM;
    short* cw_wo_bl  = cw_wo_sw  + (size_t)4  * DIM * DIM;
    short* cw_w1_sw  = cw_wo_bl  + (size_t)12 * DIM * DIM;
    short* cw_w1_bl  = cw_w1_sw  + (size_t)4  * MLP_H * DIM;
    short* cw_w2_sw  = cw_w1_bl  + (size_t)12 * MLP_H * DIM;
    short* cw_w2_bl  = cw_w2_sw  + (size_t)4  * DIM * MLP_H;

    // ---- weight conversion ----
    conv_qkv_kernel<<<(4 * QP * DIM / 4 + 255) / 256, 256, 0, stream>>>(SW_WQ, SW_WK, SW_WV, cw_qkv_sw, 4);
    conv_qkv_kernel<<<(12 * QP * DIM / 4 + 255) / 256, 256, 0, stream>>>(BL_WQ, BL_WK, BL_WV, cw_qkv_bl, 12);
    conv_kernel<<<(4 * DIM * DIM / 4 + 255) / 256, 256, 0, stream>>>(SW_WO, cw_wo_sw, 4 * DIM * DIM);
    conv_kernel<<<(12 * DIM * DIM / 4 + 255) / 256, 256, 0, stream>>>(BL_WO, cw_wo_bl, 12 * DIM * DIM);
    conv_kernel<<<(4 * MLP_H * DIM / 4 + 255) / 256, 256, 0, stream>>>(SW_W1, cw_w1_sw, 4 * MLP_H * DIM);
    conv_kernel<<<(12 * MLP_H * DIM / 4 + 255) / 256, 256, 0, stream>>>(BL_W1, cw_w1_bl, 12 * MLP_H * DIM);
    conv_kernel<<<(4 * DIM * MLP_H / 4 + 255) / 256, 256, 0, stream>>>(SW_W2, cw_w2_sw, 4 * DIM * MLP_H);
    conv_kernel<<<(12 * DIM * MLP_H / 4 + 255) / 256, 256, 0, stream>>>(BL_W2, cw_w2_bl, 12 * DIM * MLP_H);

    rel_kernel<<<BATCH * N1 * N1 / 256, 256, 0, stream>>>(X0, RW1, RB1, RWP, RBP, rel);
    hipMemcpyAsync(xa, X, sizeof(float) * T1 * DIM, hipMemcpyDeviceToDevice, stream);

    // ---------------- phase 1: sw layers (N=256) ----------------
    dim3 gQ1(QP / 64, T1 / 64);
    dim3 gP1(DIM / 64, T1 / 64);
    dim3 gM1(MLP_H / 64, T1 / 64);
    dim3 gF1(4, HEADS, BATCH);
    for (int l = 0; l < 4; l++) {
        const short* wqkv = cw_qkv_sw + (size_t)l * QP * DIM;
        const short* wo = cw_wo_sw + (size_t)l * DIM * DIM;
        const short* w1 = cw_w1_sw + (size_t)l * MLP_H * DIM;
        const short* w2 = cw_w2_sw + (size_t)l * DIM * MLP_H;
        const float* bo = SW_BO + (size_t)l * DIM;
        const float* b1 = SW_B1 + (size_t)l * MLP_H;
        const float* b2 = SW_B2 + (size_t)l * DIM;

        ln_kernel<<<T1, 128, 0, stream>>>(xa, SW_LN1G + l * DIM, SW_LN1B + l * DIM, xn);
        gemm_bf16_kernel<<<gQ1, 256, 0, stream>>>(xn, wqkv, nullptr, nullptr, nullptr,
                                                  nullptr, qkv, T1, QP, DIM, 0);
        if (l == 0)
            attn_rel_mfma_kernel<<<gF1, 256, 0, stream>>>(qkv, rel, MSK, ab);
        else
            attn_mfma_kernel<<<gF1, 256, 0, stream>>>(qkv, MSK, ab, N1);
        gemm_bf16_kernel<<<gP1, 256, 0, stream>>>(ab, wo, bo, xa, nullptr,
                                                  xa, nullptr, T1, DIM, DIM, 2);
        ln_kernel<<<T1, 128, 0, stream>>>(xa, SW_LN2G + l * DIM, SW_LN2B + l * DIM, xn);
        gemm_bf16_kernel<<<gM1, 256, 0, stream>>>(xn, w1, b1, nullptr, nullptr,
                                                  nullptr, hb, T1, MLP_H, DIM, 1);
        gemm_bf16_kernel<<<gP1, 256, 0, stream>>>(hb, w2, b2, xa, nullptr,
                                                  xa, nullptr, T1, DIM, MLP_H, 2);
    }

    // ---------------- concat cls ----------------
    concat_kernel<<<(BATCH * N2 * DIM + 255) / 256, 256, 0, stream>>>(xa, CLSW, MSK, xb, m2);

    // ---------------- phase 2: bl layers (N=257) ----------------
    int MB2 = (T2 + 63) / 64;
    dim3 gQ2(QP / 64, MB2);
    dim3 gP2(DIM / 64, MB2);
    dim3 gM2(MLP_H / 64, MB2);
    dim3 gF2(5, HEADS, BATCH);
    for (int l = 0; l < 12; l++) {
        const short* wqkv = cw_qkv_bl + (size_t)l * QP * DIM;
        const short* wo = cw_wo_bl + (size_t)l * DIM * DIM;
        const short* w1 = cw_w1_bl + (size_t)l * MLP_H * DIM;
        const short* w2 = cw_w2_bl + (size_t)l * DIM * MLP_H;
        const float* bo = BL_BO + (size_t)l * DIM;
        const float* b1 = BL_B1 + (size_t)l * MLP_H;
        const float* b2 = BL_B2 + (size_t)l * DIM;
        const float* g1 = BL_G1 + (size_t)l * DIM;
        const float* g2 = BL_G2 + (size_t)l * DIM;

        ln_kernel<<<T2, 128, 0, stream>>>(xb, BL_LN1G + l * DIM, BL_LN1B + l * DIM, xn);
        gemm_bf16_kernel<<<gQ2, 256, 0, stream>>>(xn, wqkv, nullptr, nullptr, nullptr,
                                                  nullptr, qkv, T2, QP, DIM, 0);
        attn_mfma_kernel<<<gF2, 256, 0, stream>>>(qkv, m2, ab, N2);
        gemm_bf16_kernel<<<gP2, 256, 0, stream>>>(ab, wo, bo, xb, g1,
                                                  xb, nullptr, T2, DIM, DIM, 2);
        ln_kernel<<<T2, 128, 0, stream>>>(xb, BL_LN2G + l * DIM, BL_LN2B + l * DIM, xn);
        gemm_bf16_kernel<<<gM2, 256, 0, stream>>>(xn, w1, b1, nullptr, nullptr,
                                                  nullptr, hb, T2, MLP_H, DIM, 1);
        gemm_bf16_kernel<<<gP2, 256, 0, stream>>>(hb, w2, b2, xb, g2,
                                                  xb, nullptr, T2, DIM, MLP_H, 2);
    }

    // ---------------- head ----------------
    head_kernel<<<BATCH * 3, 64, 0, stream>>>(xb, OUTW, OUTB, (float*)d_out);
}

// Round 8
// 1831.649 us; speedup vs baseline: 3.0144x; 1.0952x over previous
//
#include <hip/hip_runtime.h>
#include <hip/hip_bf16.h>
#include <math.h>

#define DIM 384
#define HEADS 12
#define HD 32
#define MLP_H 1536
#define BATCH 8
#define N1 256
#define N2 257
#define QP 1152          // fused qkv row pitch (shorts)
#define SCALE 0.17677669529663687f
#define TIME_SCALE 18.0f

typedef __attribute__((ext_vector_type(8))) short frag8;
typedef __attribute__((ext_vector_type(4))) float f32x4;

__device__ inline short f2bf(float x) {
    __hip_bfloat16 h = __float2bfloat16(x);
    short s;
    __builtin_memcpy(&s, &h, 2);
    return s;
}
__device__ inline float bf2f(short s) {
    unsigned u = ((unsigned)(unsigned short)s) << 16;
    float f;
    __builtin_memcpy(&f, &u, 4);
    return f;
}

// ------------------------------------------------------------------
// weight conversion: fp32 -> bf16 (plain)
// ------------------------------------------------------------------
__global__ __launch_bounds__(256) void conv_kernel(
        const float* __restrict__ in, short* __restrict__ out, int n) {
    int i = (blockIdx.x * 256 + threadIdx.x) * 4;
    if (i >= n) return;
    float4 v = *(const float4*)(in + i);
    out[i]     = f2bf(v.x);
    out[i + 1] = f2bf(v.y);
    out[i + 2] = f2bf(v.z);
    out[i + 3] = f2bf(v.w);
}

// gather-convert: per layer pack [wq;wk;wv] -> (L,1152,384) bf16
__global__ __launch_bounds__(256) void conv_qkv_kernel(
        const float* __restrict__ wq, const float* __restrict__ wk,
        const float* __restrict__ wv, short* __restrict__ out, int L) {
    size_t idx = ((size_t)blockIdx.x * 256 + threadIdx.x) * 4;
    size_t total = (size_t)L * QP * DIM;
    if (idx >= total) return;
    size_t k = idx % DIM;
    size_t row = idx / DIM;
    size_t r = row % QP;
    size_t l = row / QP;
    int which = (int)(r / DIM);
    int rr = (int)(r % DIM);
    const float* src = ((which == 0) ? wq : (which == 1) ? wk : wv)
                     + (l * DIM + rr) * DIM + k;
    float4 v = *(const float4*)src;
    out[idx]     = f2bf(v.x);
    out[idx + 1] = f2bf(v.y);
    out[idx + 2] = f2bf(v.z);
    out[idx + 3] = f2bf(v.w);
}

// ------------------------------------------------------------------
// rel bias -> bf16
// ------------------------------------------------------------------
__global__ __launch_bounds__(256) void rel_kernel(
        const float* __restrict__ x0, const float* __restrict__ w1d,
        const float* __restrict__ b1d, const float* __restrict__ wp,
        const float* __restrict__ bp, short* __restrict__ rel) {
    __shared__ float swp[HD * HD];
    __shared__ float sbp[HD];
    __shared__ float sw1[8];
    __shared__ float sb1;
    __shared__ float sfreq[16];
    int tid = threadIdx.x;
    for (int i = tid; i < HD * HD; i += 256) swp[i] = wp[i];
    if (tid < HD) sbp[tid] = bp[tid];
    if (tid < 8) sw1[tid] = w1d[tid];
    if (tid == 0) sb1 = b1d[0];
    if (tid < 16) sfreq[tid] = expf(-(float)tid * 0.5756462732485114f);
    __syncthreads();

    int gid = blockIdx.x * 256 + tid;
    int j  = gid & (N1 - 1);
    int bi = gid >> 8;
    int i  = bi & (N1 - 1);
    int b  = bi >> 8;

    const float* pi = x0 + (size_t)(b * N1 + i) * 4;
    const float* pj = x0 + (size_t)(b * N1 + j) * 4;
    float dx = pi[0] - pj[0], dy = pi[1] - pj[1], dz = pi[2] - pj[2];
    float dt = pi[3] - pj[3] * TIME_SCALE;
    float dx2 = dx * dx, dy2 = dy * dy, dz2 = dz * dz, dt2 = dt * dt;
    float ds2 = dx2 + dy2 + dz2 - dt2;
    float d = copysignf(sqrtf(fabsf(ds2)), ds2);
    d += dx * sw1[0] + dy * sw1[1] + dz * sw1[2] + dt * sw1[3]
       + dx2 * sw1[4] + dy2 * sw1[5] + dz2 * sw1[6] + dt2 * sw1[7] + sb1;
    d = fminf(fmaxf(d, -4.f), 4.f) * 1024.f;

    float emb[32];
    #pragma unroll
    for (int k = 0; k < 16; k++) {
        float s, c;
        sincosf(d * sfreq[k], &s, &c);
        emb[k] = s; emb[16 + k] = c;
    }
    short* out = rel + (size_t)gid * HD;
    #pragma unroll 4
    for (int c = 0; c < HD; c++) {
        float a = sbp[c];
        #pragma unroll
        for (int k = 0; k < 32; k++) a += emb[k] * swp[c * 32 + k];
        out[c] = f2bf(a);
    }
}

// ------------------------------------------------------------------
// LayerNorm: fp32 in -> bf16 out
// ------------------------------------------------------------------
__global__ __launch_bounds__(128) void ln_kernel(
        const float* __restrict__ x, const float* __restrict__ g,
        const float* __restrict__ b, short* __restrict__ y) {
    int r = blockIdx.x;
    int t = threadIdx.x;
    const float* xr = x + (size_t)r * DIM;
    float v0 = xr[t], v1 = xr[t + 128], v2 = xr[t + 256];
    __shared__ float redm[2], redv[2];
    float s = v0 + v1 + v2;
    for (int o = 32; o; o >>= 1) s += __shfl_down(s, o, 64);
    int lane = t & 63, wid = t >> 6;
    if (!lane) redm[wid] = s;
    __syncthreads();
    float mean = (redm[0] + redm[1]) * (1.f / DIM);
    float d0 = v0 - mean, d1 = v1 - mean, d2 = v2 - mean;
    float s2 = d0 * d0 + d1 * d1 + d2 * d2;
    for (int o = 32; o; o >>= 1) s2 += __shfl_down(s2, o, 64);
    if (!lane) redv[wid] = s2;
    __syncthreads();
    float var = (redv[0] + redv[1]) * (1.f / DIM);
    float rs = rsqrtf(var + 1e-5f);
    short* yr = y + (size_t)r * DIM;
    yr[t]       = f2bf(d0 * rs * g[t]       + b[t]);
    yr[t + 128] = f2bf(d1 * rs * g[t + 128] + b[t + 128]);
    yr[t + 256] = f2bf(d2 * rs * g[t + 256] + b[t + 256]);
}

// ------------------------------------------------------------------
// bf16 MFMA GEMM v2: 512 thr (8 waves). BK=128 per iteration;
// wave-group g = w>>2 computes K-half g of each chunk; partials
// combined via SoA f32x4 LDS reduce; register-prefetch double buffer.
// mode 0: ->bf16 Cb. mode 1: bias+GELU ->bf16 Cb.
// mode 2: bias + resid (+gate) ->fp32 Cf.
// ------------------------------------------------------------------
__global__ __launch_bounds__(512) void gemm_bf16_kernel(
        const short* __restrict__ A, const short* __restrict__ W,
        const float* __restrict__ bias, const float* __restrict__ resid,
        const float* __restrict__ gvec, float* __restrict__ Cf,
        short* __restrict__ Cb, int M, int Np, int K, int mode) {
    __shared__ short As2[2][2][4][64][8];   // [kh][ks][q][row][j]  16 KB
    __shared__ short Bs2[2][2][4][64][8];   // 16 KB
    int tid = threadIdx.x;
    int w = tid >> 6, lane = tid & 63;
    int nlo = lane & 15, quad = lane >> 4;
    int g = w >> 2, wl = w & 3;
    int wm = wl >> 1, wn = wl & 1;
    int n0 = blockIdx.x * 64, m0 = blockIdx.y * 64;

    f32x4 acc00 = {0.f, 0.f, 0.f, 0.f}, acc01 = {0.f, 0.f, 0.f, 0.f};
    f32x4 acc10 = {0.f, 0.f, 0.f, 0.f}, acc11 = {0.f, 0.f, 0.f, 0.f};

    int oct16 = tid & 15, rbase = tid >> 4;     // rows rbase, rbase+32
    int kh_s = oct16 >> 3, oo = oct16 & 7, ks_s = oo >> 2, q_s = oo & 3;
    const frag8 fz = {0, 0, 0, 0, 0, 0, 0, 0};
    frag8 pa0 = fz, pa1 = fz, pb0, pb1;

    {   // prefetch k0 = 0
        int gm0 = m0 + rbase, gm1 = m0 + rbase + 32;
        if (gm0 < M) pa0 = *(const frag8*)(A + (size_t)gm0 * K + oct16 * 8);
        if (gm1 < M) pa1 = *(const frag8*)(A + (size_t)gm1 * K + oct16 * 8);
        pb0 = *(const frag8*)(W + (size_t)(n0 + rbase) * K + oct16 * 8);
        pb1 = *(const frag8*)(W + (size_t)(n0 + rbase + 32) * K + oct16 * 8);
    }

    for (int k0 = 0; k0 < K; k0 += 128) {
        *(frag8*)&As2[kh_s][ks_s][q_s][rbase][0]      = pa0;
        *(frag8*)&As2[kh_s][ks_s][q_s][rbase + 32][0] = pa1;
        *(frag8*)&Bs2[kh_s][ks_s][q_s][rbase][0]      = pb0;
        *(frag8*)&Bs2[kh_s][ks_s][q_s][rbase + 32][0] = pb1;
        __syncthreads();
        int kn = k0 + 128;
        if (kn < K) {
            int gm0 = m0 + rbase, gm1 = m0 + rbase + 32;
            pa0 = fz; pa1 = fz;
            if (gm0 < M) pa0 = *(const frag8*)(A + (size_t)gm0 * K + kn + oct16 * 8);
            if (gm1 < M) pa1 = *(const frag8*)(A + (size_t)gm1 * K + kn + oct16 * 8);
            pb0 = *(const frag8*)(W + (size_t)(n0 + rbase) * K + kn + oct16 * 8);
            pb1 = *(const frag8*)(W + (size_t)(n0 + rbase + 32) * K + kn + oct16 * 8);
        }
        #pragma unroll
        for (int ks = 0; ks < 2; ks++) {
            frag8 a0 = *(const frag8*)&As2[g][ks][quad][wm * 32 + nlo][0];
            frag8 a1 = *(const frag8*)&As2[g][ks][quad][wm * 32 + 16 + nlo][0];
            frag8 b0 = *(const frag8*)&Bs2[g][ks][quad][wn * 32 + nlo][0];
            frag8 b1 = *(const frag8*)&Bs2[g][ks][quad][wn * 32 + 16 + nlo][0];
            acc00 = __builtin_amdgcn_mfma_f32_16x16x32_bf16(a0, b0, acc00, 0, 0, 0);
            acc01 = __builtin_amdgcn_mfma_f32_16x16x32_bf16(a0, b1, acc01, 0, 0, 0);
            acc10 = __builtin_amdgcn_mfma_f32_16x16x32_bf16(a1, b0, acc10, 0, 0, 0);
            acc11 = __builtin_amdgcn_mfma_f32_16x16x32_bf16(a1, b1, acc11, 0, 0, 0);
        }
        __syncthreads();
    }

    // ---- combine wave-group partials (SoA, conflict-free) ----
    f32x4* red4 = (f32x4*)&As2[0][0][0][0][0];   // 4*256 f32x4 = 16 KB
    int roff = wl * 64 + lane;
    if (g == 1) {
        red4[roff]       = acc00;
        red4[256 + roff] = acc01;
        red4[512 + roff] = acc10;
        red4[768 + roff] = acc11;
    }
    __syncthreads();
    if (g == 1) return;
    {
        f32x4 t0 = red4[roff], t1 = red4[256 + roff];
        f32x4 t2 = red4[512 + roff], t3 = red4[768 + roff];
        #pragma unroll
        for (int r = 0; r < 4; r++) {
            acc00[r] += t0[r]; acc01[r] += t1[r];
            acc10[r] += t2[r]; acc11[r] += t3[r];
        }
    }

    // ---- epilogue (group 0 only) ----
    #pragma unroll
    for (int mi = 0; mi < 2; mi++) {
        #pragma unroll
        for (int nf = 0; nf < 2; nf++) {
            f32x4 av = (mi == 0) ? ((nf == 0) ? acc00 : acc01)
                                 : ((nf == 0) ? acc10 : acc11);
            int col = n0 + wn * 32 + nf * 16 + nlo;
            float bcol = (mode >= 1) ? bias[col] : 0.f;
            float gs = 1.f;
            if (mode == 2 && gvec) gs = gvec[col];
            #pragma unroll
            for (int r = 0; r < 4; r++) {
                int row = m0 + wm * 32 + mi * 16 + quad * 4 + r;
                if (row >= M) continue;
                float v = av[r] + bcol;
                if (mode == 1) v = 0.5f * v * (1.f + erff(v * 0.70710678118654752f));
                if (mode == 2) {
                    Cf[(size_t)row * Np + col] = resid[(size_t)row * Np + col] + gs * v;
                } else {
                    Cb[(size_t)row * Np + col] = f2bf(v);
                }
            }
        }
    }
}

// ------------------------------------------------------------------
// MFMA flash attention (no rel) — verified R5/R6
// ------------------------------------------------------------------
__global__ __launch_bounds__(256) void attn_mfma_kernel(
        const short* __restrict__ qkv, const float* __restrict__ maskv,
        short* __restrict__ ob, int Nseq) {
    __shared__ short kf[18][64][8];
    __shared__ short vf[9][2][64][8];
    __shared__ short pbuf[4][16][40];
    __shared__ float ms[320];

    int tid = threadIdx.x;
    int w = tid >> 6, lane = tid & 63;
    int n = lane & 15, quad = lane >> 4;
    int qg = blockIdx.x, h = blockIdx.y, b = blockIdx.z;
    size_t rowB = (size_t)(b * Nseq);

    for (int j = tid; j < 320; j += 256)
        ms[j] = (j < Nseq) ? maskv[b * Nseq + j] : 0.f;

    {
        int c0 = (tid & 3) * 8;
        for (int j = tid >> 2; j < 288; j += 64) {
            frag8 kk = {0, 0, 0, 0, 0, 0, 0, 0};
            frag8 vv = {0, 0, 0, 0, 0, 0, 0, 0};
            if (j < Nseq) {
                const short* base = qkv + (rowB + j) * QP + h * HD + c0;
                kk = *(const frag8*)(base + 384);
                vv = *(const frag8*)(base + 768);
            }
            *(frag8*)&kf[j >> 4][(c0 >> 3) * 16 + (j & 15)][0] = kk;
            #pragma unroll
            for (int e = 0; e < 8; e++) {
                int c = c0 + e;
                vf[j >> 5][c >> 4][((j & 31) >> 3) * 16 + (c & 15)][j & 7] = vv[e];
            }
        }
    }

    int i0 = qg * 64 + w * 16;
    frag8 qa = {0, 0, 0, 0, 0, 0, 0, 0};
    {
        int i = i0 + n;
        if (i < Nseq) qa = *(const frag8*)(qkv + (rowB + i) * QP + h * HD + quad * 8);
    }
    __syncthreads();

    float msq[4];
    #pragma unroll
    for (int r = 0; r < 4; r++) msq[r] = ms[i0 + quad * 4 + r];

    float mrow[4], lsum[4];
    #pragma unroll
    for (int r = 0; r < 4; r++) { mrow[r] = -3.0e38f; lsum[r] = 0.f; }
    f32x4 oacc0 = {0.f, 0.f, 0.f, 0.f}, oacc1 = {0.f, 0.f, 0.f, 0.f};

    for (int jb = 0; jb < 9; jb++) {
        frag8 kb0 = *(const frag8*)&kf[2 * jb][lane][0];
        frag8 kb1 = *(const frag8*)&kf[2 * jb + 1][lane][0];
        f32x4 z = {0.f, 0.f, 0.f, 0.f};
        f32x4 s0 = __builtin_amdgcn_mfma_f32_16x16x32_bf16(qa, kb0, z, 0, 0, 0);
        f32x4 s1 = __builtin_amdgcn_mfma_f32_16x16x32_bf16(qa, kb1, z, 0, 0, 0);

        int j0 = jb * 32 + n;
        int j1 = j0 + 16;
        float mj0 = ms[j0], mj1 = ms[j1];
        float pad0 = (j0 < Nseq) ? 0.f : -1e9f;
        float pad1 = (j1 < Nseq) ? 0.f : -1e9f;

        #pragma unroll
        for (int r = 0; r < 4; r++) {
            float mi = msq[r];
            float b0 = ((fmaxf(mi, mj0) < 0.f) ? 0.f : fminf(mi, mj0)) + pad0;
            float b1 = ((fmaxf(mi, mj1) < 0.f) ? 0.f : fminf(mi, mj1)) + pad1;
            float v0 = s0[r] * SCALE + b0;
            float v1 = s1[r] * SCALE + b1;
            float rm = fmaxf(v0, v1);
            rm = fmaxf(rm, __shfl_xor(rm, 1));
            rm = fmaxf(rm, __shfl_xor(rm, 2));
            rm = fmaxf(rm, __shfl_xor(rm, 4));
            rm = fmaxf(rm, __shfl_xor(rm, 8));
            float mn = fmaxf(mrow[r], rm);
            float alpha = __expf(mrow[r] - mn);
            mrow[r] = mn;
            float p0 = __expf(v0 - mn);
            float p1 = __expf(v1 - mn);
            float ps = p0 + p1;
            ps += __shfl_xor(ps, 1);
            ps += __shfl_xor(ps, 2);
            ps += __shfl_xor(ps, 4);
            ps += __shfl_xor(ps, 8);
            lsum[r] = lsum[r] * alpha + ps;
            oacc0[r] *= alpha;
            oacc1[r] *= alpha;
            pbuf[w][quad * 4 + r][n]      = f2bf(p0);
            pbuf[w][quad * 4 + r][n + 16] = f2bf(p1);
        }
        __syncthreads();
        frag8 pa = *(const frag8*)&pbuf[w][n][quad * 8];
        frag8 vb0 = *(const frag8*)&vf[jb][0][lane][0];
        frag8 vb1 = *(const frag8*)&vf[jb][1][lane][0];
        oacc0 = __builtin_amdgcn_mfma_f32_16x16x32_bf16(pa, vb0, oacc0, 0, 0, 0);
        oacc1 = __builtin_amdgcn_mfma_f32_16x16x32_bf16(pa, vb1, oacc1, 0, 0, 0);
        __syncthreads();
    }

    #pragma unroll
    for (int r = 0; r < 4; r++) {
        int i = i0 + quad * 4 + r;
        if (i < Nseq) {
            float invl = 1.f / lsum[r];
            ob[(rowB + i) * DIM + h * HD + n]      = f2bf(oacc0[r] * invl);
            ob[(rowB + i) * DIM + h * HD + 16 + n] = f2bf(oacc1[r] * invl);
        }
    }
}

// ------------------------------------------------------------------
// MFMA flash attention WITH rel bias (layer 0, Nseq == N1 == 256).
// ------------------------------------------------------------------
__global__ __launch_bounds__(256) void attn_rel_mfma_kernel(
        const short* __restrict__ qkv, const short* __restrict__ relb,
        const float* __restrict__ maskv, short* __restrict__ ob) {
    const int Nseq = N1;
    __shared__ short kf[16][64][8];
    __shared__ short vf[8][2][64][8];
    __shared__ short pbuf[4][16][40];
    __shared__ float qrow[4][16][32];
    __shared__ float orel[4][16][33];
    __shared__ float alphas[4][16];
    __shared__ float ms[256];

    int tid = threadIdx.x;
    int w = tid >> 6, lane = tid & 63;
    int n = lane & 15, quad = lane >> 4;
    int qg = blockIdx.x, h = blockIdx.y, b = blockIdx.z;
    size_t rowB = (size_t)(b * Nseq);

    if (tid < 256) ms[tid] = maskv[b * Nseq + tid];

    {
        int c0 = (tid & 3) * 8;
        for (int j = tid >> 2; j < 256; j += 64) {
            const short* base = qkv + (rowB + j) * QP + h * HD + c0;
            frag8 kk = *(const frag8*)(base + 384);
            frag8 vv = *(const frag8*)(base + 768);
            *(frag8*)&kf[j >> 4][(c0 >> 3) * 16 + (j & 15)][0] = kk;
            #pragma unroll
            for (int e = 0; e < 8; e++) {
                int c = c0 + e;
                vf[j >> 5][c >> 4][((j & 31) >> 3) * 16 + (c & 15)][j & 7] = vv[e];
            }
        }
    }

    int i0 = qg * 64 + w * 16;
    frag8 qa = *(const frag8*)(qkv + (rowB + i0 + n) * QP + h * HD + quad * 8);
    {
        int il = lane >> 2, c8 = (lane & 3) * 8;
        frag8 qv = *(const frag8*)(qkv + (rowB + i0 + il) * QP + h * HD + c8);
        #pragma unroll
        for (int e = 0; e < 8; e++) qrow[w][il][c8 + e] = bf2f(qv[e]) * SCALE;
    }
    __syncthreads();

    float msq[4];
    #pragma unroll
    for (int r = 0; r < 4; r++) msq[r] = ms[i0 + quad * 4 + r];

    float mrow[4], lsum[4];
    #pragma unroll
    for (int r = 0; r < 4; r++) { mrow[r] = -3.0e38f; lsum[r] = 0.f; }
    f32x4 oacc0 = {0.f, 0.f, 0.f, 0.f}, oacc1 = {0.f, 0.f, 0.f, 0.f};
    float arel[8];
    #pragma unroll
    for (int e = 0; e < 8; e++) arel[e] = 0.f;

    int il = lane & 15, oct = lane >> 4;
    const short* relrow = relb + (((size_t)b * N1 + (i0 + il)) * N1) * HD + oct * 8;

    for (int jb = 0; jb < 8; jb++) {
        frag8 kb0 = *(const frag8*)&kf[2 * jb][lane][0];
        frag8 kb1 = *(const frag8*)&kf[2 * jb + 1][lane][0];
        f32x4 z = {0.f, 0.f, 0.f, 0.f};
        f32x4 s0 = __builtin_amdgcn_mfma_f32_16x16x32_bf16(qa, kb0, z, 0, 0, 0);
        f32x4 s1 = __builtin_amdgcn_mfma_f32_16x16x32_bf16(qa, kb1, z, 0, 0, 0);

        int j0 = jb * 32 + n;
        int j1 = j0 + 16;
        float mj0 = ms[j0], mj1 = ms[j1];

        #pragma unroll
        for (int r = 0; r < 4; r++) {
            int i = i0 + quad * 4 + r;
            const short* r0 = relb + (((size_t)b * N1 + i) * N1 + j0) * HD;
            const short* r1 = relb + (((size_t)b * N1 + i) * N1 + j1) * HD;
            float d0 = 0.f, d1 = 0.f;
            #pragma unroll
            for (int c8 = 0; c8 < 4; c8++) {
                frag8 ra = *(const frag8*)(r0 + c8 * 8);
                frag8 rb_ = *(const frag8*)(r1 + c8 * 8);
                const float* qp = &qrow[w][quad * 4 + r][c8 * 8];
                #pragma unroll
                for (int e = 0; e < 8; e++) {
                    float qv = qp[e];
                    d0 += qv * bf2f(ra[e]);
                    d1 += qv * bf2f(rb_[e]);
                }
            }
            float mi = msq[r];
            float b0 = (fmaxf(mi, mj0) < 0.f) ? 0.f : fminf(mi, mj0);
            float b1 = (fmaxf(mi, mj1) < 0.f) ? 0.f : fminf(mi, mj1);
            float v0 = s0[r] * SCALE + d0 + b0;
            float v1 = s1[r] * SCALE + d1 + b1;
            float rm = fmaxf(v0, v1);
            rm = fmaxf(rm, __shfl_xor(rm, 1));
            rm = fmaxf(rm, __shfl_xor(rm, 2));
            rm = fmaxf(rm, __shfl_xor(rm, 4));
            rm = fmaxf(rm, __shfl_xor(rm, 8));
            float mn = fmaxf(mrow[r], rm);
            float alpha = __expf(mrow[r] - mn);
            mrow[r] = mn;
            float p0 = __expf(v0 - mn);
            float p1 = __expf(v1 - mn);
            float ps = p0 + p1;
            ps += __shfl_xor(ps, 1);
            ps += __shfl_xor(ps, 2);
            ps += __shfl_xor(ps, 4);
            ps += __shfl_xor(ps, 8);
            lsum[r] = lsum[r] * alpha + ps;
            oacc0[r] *= alpha;
            oacc1[r] *= alpha;
            pbuf[w][quad * 4 + r][n]      = f2bf(p0);
            pbuf[w][quad * 4 + r][n + 16] = f2bf(p1);
            if (n == 0) alphas[w][quad * 4 + r] = alpha;
        }
        __syncthreads();
        {
            float al = alphas[w][il];
            #pragma unroll
            for (int e = 0; e < 8; e++) arel[e] *= al;
            const short* rb2 = relrow + (size_t)(jb * 32) * HD;
            #pragma unroll 8
            for (int jj = 0; jj < 32; jj++) {
                float p = bf2f(pbuf[w][il][jj]);
                frag8 rv = *(const frag8*)(rb2 + (size_t)jj * HD);
                #pragma unroll
                for (int e = 0; e < 8; e++) arel[e] += p * bf2f(rv[e]);
            }
        }
        frag8 pa = *(const frag8*)&pbuf[w][n][quad * 8];
        frag8 vb0 = *(const frag8*)&vf[jb][0][lane][0];
        frag8 vb1 = *(const frag8*)&vf[jb][1][lane][0];
        oacc0 = __builtin_amdgcn_mfma_f32_16x16x32_bf16(pa, vb0, oacc0, 0, 0, 0);
        oacc1 = __builtin_amdgcn_mfma_f32_16x16x32_bf16(pa, vb1, oacc1, 0, 0, 0);
        __syncthreads();
    }

    #pragma unroll
    for (int e = 0; e < 8; e++) orel[w][il][oct * 8 + e] = arel[e];
    __syncthreads();

    #pragma unroll
    for (int r = 0; r < 4; r++) {
        int i = i0 + quad * 4 + r;
        float invl = 1.f / lsum[r];
        float o0 = (oacc0[r] + orel[w][quad * 4 + r][n])      * invl;
        float o1 = (oacc1[r] + orel[w][quad * 4 + r][16 + n]) * invl;
        ob[(rowB + i) * DIM + h * HD + n]      = f2bf(o0);
        ob[(rowB + i) * DIM + h * HD + 16 + n] = f2bf(o1);
    }
}

// ------------------------------------------------------------------
__global__ __launch_bounds__(256) void concat_kernel(
        const float* __restrict__ xa, const float* __restrict__ clsw,
        const float* __restrict__ mask, float* __restrict__ xb,
        float* __restrict__ m2) {
    int idx = blockIdx.x * 256 + threadIdx.x;
    const int total = BATCH * N2 * DIM;
    if (idx < total) {
        int c = idx % DIM;
        int tokb = idx / DIM;
        int p = tokb % N2, b = tokb / N2;
        xb[idx] = (p == 0) ? clsw[c] : xa[((size_t)(b * N1) + p - 1) * DIM + c];
    }
    if (idx < BATCH * N2) {
        int p = idx % N2, b = idx / N2;
        m2[idx] = (p == 0) ? 0.f : mask[b * N1 + p - 1];
    }
}

__global__ __launch_bounds__(64) void head_kernel(
        const float* __restrict__ xb, const float* __restrict__ ow,
        const float* __restrict__ obv, float* __restrict__ out) {
    int blk = blockIdx.x;
    int b = blk / 3, o = blk % 3;
    int lane = threadIdx.x;
    const float* xr = xb + (size_t)(b * N2) * DIM;
    const float* wr = ow + o * DIM;
    float s = 0.f;
    for (int c = lane; c < DIM; c += 64) s += xr[c] * wr[c];
    for (int off = 32; off; off >>= 1) s += __shfl_down(s, off, 64);
    if (!lane) out[blk] = s + obv[o];
}

// ------------------------------------------------------------------
extern "C" void kernel_launch(void* const* d_in, const int* in_sizes, int n_in,
                              void* d_out, int out_size, void* d_ws, size_t ws_size,
                              hipStream_t stream) {
    (void)in_sizes; (void)n_in; (void)out_size; (void)ws_size;
    const float* X       = (const float*)d_in[0];
    const float* X0      = (const float*)d_in[1];
    const float* MSK     = (const float*)d_in[2];
    const float* RW1     = (const float*)d_in[3];
    const float* RB1     = (const float*)d_in[4];
    const float* RWP     = (const float*)d_in[5];
    const float* RBP     = (const float*)d_in[6];
    const float* SW_LN1G = (const float*)d_in[7];
    const float* SW_LN1B = (const float*)d_in[8];
    const float* SW_LN2G = (const float*)d_in[9];
    const float* SW_LN2B = (const float*)d_in[10];
    const float* SW_WQ   = (const float*)d_in[11];
    const float* SW_WK   = (const float*)d_in[12];
    const float* SW_WV   = (const float*)d_in[13];
    const float* SW_WO   = (const float*)d_in[14];
    const float* SW_BO   = (const float*)d_in[15];
    const float* SW_W1   = (const float*)d_in[16];
    const float* SW_B1   = (const float*)d_in[17];
    const float* SW_W2   = (const float*)d_in[18];
    const float* SW_B2   = (const float*)d_in[19];
    const float* BL_LN1G = (const float*)d_in[20];
    const float* BL_LN1B = (const float*)d_in[21];
    const float* BL_LN2G = (const float*)d_in[22];
    const float* BL_LN2B = (const float*)d_in[23];
    const float* BL_WQ   = (const float*)d_in[24];
    const float* BL_WK   = (const float*)d_in[25];
    const float* BL_WV   = (const float*)d_in[26];
    const float* BL_WO   = (const float*)d_in[27];
    const float* BL_BO   = (const float*)d_in[28];
    const float* BL_W1   = (const float*)d_in[29];
    const float* BL_B1   = (const float*)d_in[30];
    const float* BL_W2   = (const float*)d_in[31];
    const float* BL_B2   = (const float*)d_in[32];
    const float* BL_G1   = (const float*)d_in[33];
    const float* BL_G2   = (const float*)d_in[34];
    const float* CLSW    = (const float*)d_in[35];
    const float* OUTW    = (const float*)d_in[36];
    const float* OUTB    = (const float*)d_in[37];

    const int T1 = BATCH * N1;   // 2048
    const int T2 = BATCH * N2;   // 2056
    const size_t RELSZ = (size_t)BATCH * N1 * N1 * HD;   // shorts

    short* rel = (short*)d_ws;
    float* xa  = (float*)(rel + RELSZ);
    float* xb  = xa + (size_t)T1 * DIM;
    float* m2  = xb + (size_t)T2 * DIM;
    short* sbase = (short*)(m2 + 2064);
    short* xn   = sbase;
    short* qkv  = xn  + (size_t)T2 * DIM;
    short* ab   = qkv + (size_t)T2 * QP;
    short* hb   = ab  + (size_t)T2 * DIM;
    short* cw_qkv_sw = hb + (size_t)T2 * MLP_H;
    short* cw_qkv_bl = cw_qkv_sw + (size_t)4  * QP * DIM;
    short* cw_wo_sw  = cw_qkv_bl + (size_t)12 * QP * DIM;
    short* cw_wo_bl  = cw_wo_sw  + (size_t)4  * DIM * DIM;
    short* cw_w1_sw  = cw_wo_bl  + (size_t)12 * DIM * DIM;
    short* cw_w1_bl  = cw_w1_sw  + (size_t)4  * MLP_H * DIM;
    short* cw_w2_sw  = cw_w1_bl  + (size_t)12 * MLP_H * DIM;
    short* cw_w2_bl  = cw_w2_sw  + (size_t)4  * DIM * MLP_H;

    // ---- weight conversion ----
    conv_qkv_kernel<<<(4 * QP * DIM / 4 + 255) / 256, 256, 0, stream>>>(SW_WQ, SW_WK, SW_WV, cw_qkv_sw, 4);
    conv_qkv_kernel<<<(12 * QP * DIM / 4 + 255) / 256, 256, 0, stream>>>(BL_WQ, BL_WK, BL_WV, cw_qkv_bl, 12);
    conv_kernel<<<(4 * DIM * DIM / 4 + 255) / 256, 256, 0, stream>>>(SW_WO, cw_wo_sw, 4 * DIM * DIM);
    conv_kernel<<<(12 * DIM * DIM / 4 + 255) / 256, 256, 0, stream>>>(BL_WO, cw_wo_bl, 12 * DIM * DIM);
    conv_kernel<<<(4 * MLP_H * DIM / 4 + 255) / 256, 256, 0, stream>>>(SW_W1, cw_w1_sw, 4 * MLP_H * DIM);
    conv_kernel<<<(12 * MLP_H * DIM / 4 + 255) / 256, 256, 0, stream>>>(BL_W1, cw_w1_bl, 12 * MLP_H * DIM);
    conv_kernel<<<(4 * DIM * MLP_H / 4 + 255) / 256, 256, 0, stream>>>(SW_W2, cw_w2_sw, 4 * DIM * MLP_H);
    conv_kernel<<<(12 * DIM * MLP_H / 4 + 255) / 256, 256, 0, stream>>>(BL_W2, cw_w2_bl, 12 * DIM * MLP_H);

    rel_kernel<<<BATCH * N1 * N1 / 256, 256, 0, stream>>>(X0, RW1, RB1, RWP, RBP, rel);
    hipMemcpyAsync(xa, X, sizeof(float) * T1 * DIM, hipMemcpyDeviceToDevice, stream);

    // ---------------- phase 1: sw layers (N=256) ----------------
    dim3 gQ1(QP / 64, T1 / 64);
    dim3 gP1(DIM / 64, T1 / 64);
    dim3 gM1(MLP_H / 64, T1 / 64);
    dim3 gF1(4, HEADS, BATCH);
    for (int l = 0; l < 4; l++) {
        const short* wqkv = cw_qkv_sw + (size_t)l * QP * DIM;
        const short* wo = cw_wo_sw + (size_t)l * DIM * DIM;
        const short* w1 = cw_w1_sw + (size_t)l * MLP_H * DIM;
        const short* w2 = cw_w2_sw + (size_t)l * DIM * MLP_H;
        const float* bo = SW_BO + (size_t)l * DIM;
        const float* b1 = SW_B1 + (size_t)l * MLP_H;
        const float* b2 = SW_B2 + (size_t)l * DIM;

        ln_kernel<<<T1, 128, 0, stream>>>(xa, SW_LN1G + l * DIM, SW_LN1B + l * DIM, xn);
        gemm_bf16_kernel<<<gQ1, 512, 0, stream>>>(xn, wqkv, nullptr, nullptr, nullptr,
                                                  nullptr, qkv, T1, QP, DIM, 0);
        if (l == 0)
            attn_rel_mfma_kernel<<<gF1, 256, 0, stream>>>(qkv, rel, MSK, ab);
        else
            attn_mfma_kernel<<<gF1, 256, 0, stream>>>(qkv, MSK, ab, N1);
        gemm_bf16_kernel<<<gP1, 512, 0, stream>>>(ab, wo, bo, xa, nullptr,
                                                  xa, nullptr, T1, DIM, DIM, 2);
        ln_kernel<<<T1, 128, 0, stream>>>(xa, SW_LN2G + l * DIM, SW_LN2B + l * DIM, xn);
        gemm_bf16_kernel<<<gM1, 512, 0, stream>>>(xn, w1, b1, nullptr, nullptr,
                                                  nullptr, hb, T1, MLP_H, DIM, 1);
        gemm_bf16_kernel<<<gP1, 512, 0, stream>>>(hb, w2, b2, xa, nullptr,
                                                  xa, nullptr, T1, DIM, MLP_H, 2);
    }

    // ---------------- concat cls ----------------
    concat_kernel<<<(BATCH * N2 * DIM + 255) / 256, 256, 0, stream>>>(xa, CLSW, MSK, xb, m2);

    // ---------------- phase 2: bl layers (N=257) ----------------
    int MB2 = (T2 + 63) / 64;
    dim3 gQ2(QP / 64, MB2);
    dim3 gP2(DIM / 64, MB2);
    dim3 gM2(MLP_H / 64, MB2);
    dim3 gF2(5, HEADS, BATCH);
    for (int l = 0; l < 12; l++) {
        const short* wqkv = cw_qkv_bl + (size_t)l * QP * DIM;
        const short* wo = cw_wo_bl + (size_t)l * DIM * DIM;
        const short* w1 = cw_w1_bl + (size_t)l * MLP_H * DIM;
        const short* w2 = cw_w2_bl + (size_t)l * DIM * MLP_H;
        const float* bo = BL_BO + (size_t)l * DIM;
        const float* b1 = BL_B1 + (size_t)l * MLP_H;
        const float* b2 = BL_B2 + (size_t)l * DIM;
        const float* g1 = BL_G1 + (size_t)l * DIM;
        const float* g2 = BL_G2 + (size_t)l * DIM;

        ln_kernel<<<T2, 128, 0, stream>>>(xb, BL_LN1G + l * DIM, BL_LN1B + l * DIM, xn);
        gemm_bf16_kernel<<<gQ2, 512, 0, stream>>>(xn, wqkv, nullptr, nullptr, nullptr,
                                                  nullptr, qkv, T2, QP, DIM, 0);
        attn_mfma_kernel<<<gF2, 256, 0, stream>>>(qkv, m2, ab, N2);
        gemm_bf16_kernel<<<gP2, 512, 0, stream>>>(ab, wo, bo, xb, g1,
                                                  xb, nullptr, T2, DIM, DIM, 2);
        ln_kernel<<<T2, 128, 0, stream>>>(xb, BL_LN2G + l * DIM, BL_LN2B + l * DIM, xn);
        gemm_bf16_kernel<<<gM2, 512, 0, stream>>>(xn, w1, b1, nullptr, nullptr,
                                                  nullptr, hb, T2, MLP_H, DIM, 1);
        gemm_bf16_kernel<<<gP2, 512, 0, stream>>>(hb, w2, b2, xb, g2,
                                                  xb, nullptr, T2, DIM, MLP_H, 2);
    }

    // ---------------- head ----------------
    head_kernel<<<BATCH * 3, 64, 0, stream>>>(xb, OUTW, OUTB, (float*)d_out);
}